// Round 10
// baseline (5475.793 us; speedup 1.0000x reference)
//
#include <hip/hip_runtime.h>
#include <cstdint>
#include <cstddef>

#define DMODEL 512
#define NHEAD 8
#define HD 64

// ---------------------------------------------------------------- threefry
__device__ __forceinline__ uint32_t rotl32(uint32_t x, int r) {
  return (x << r) | (x >> (32 - r));
}

__device__ __forceinline__ void tf_block(uint32_t k0, uint32_t k1,
                                         uint32_t& x0, uint32_t& x1) {
  uint32_t ks0 = k0, ks1 = k1, ks2 = k0 ^ k1 ^ 0x1BD11BDAu;
  x0 += ks0; x1 += ks1;
  x0 += x1; x1 = rotl32(x1, 13); x1 ^= x0;
  x0 += x1; x1 = rotl32(x1, 15); x1 ^= x0;
  x0 += x1; x1 = rotl32(x1, 26); x1 ^= x0;
  x0 += x1; x1 = rotl32(x1, 6);  x1 ^= x0;
  x0 += ks1; x1 += ks2 + 1u;
  x0 += x1; x1 = rotl32(x1, 17); x1 ^= x0;
  x0 += x1; x1 = rotl32(x1, 29); x1 ^= x0;
  x0 += x1; x1 = rotl32(x1, 16); x1 ^= x0;
  x0 += x1; x1 = rotl32(x1, 24); x1 ^= x0;
  x0 += ks2; x1 += ks0 + 2u;
  x0 += x1; x1 = rotl32(x1, 13); x1 ^= x0;
  x0 += x1; x1 = rotl32(x1, 15); x1 ^= x0;
  x0 += x1; x1 = rotl32(x1, 26); x1 ^= x0;
  x0 += x1; x1 = rotl32(x1, 6);  x1 ^= x0;
  x0 += ks0; x1 += ks1 + 3u;
  x0 += x1; x1 = rotl32(x1, 17); x1 ^= x0;
  x0 += x1; x1 = rotl32(x1, 29); x1 ^= x0;
  x0 += x1; x1 = rotl32(x1, 16); x1 ^= x0;
  x0 += x1; x1 = rotl32(x1, 24); x1 ^= x0;
  x0 += ks1; x1 += ks2 + 4u;
  x0 += x1; x1 = rotl32(x1, 13); x1 ^= x0;
  x0 += x1; x1 = rotl32(x1, 15); x1 ^= x0;
  x0 += x1; x1 = rotl32(x1, 26); x1 ^= x0;
  x0 += x1; x1 = rotl32(x1, 6);  x1 ^= x0;
  x0 += ks2; x1 += ks0 + 5u;
}

__global__ void idx_kernel(int* __restrict__ idxb, int n, int layer, int mask) {
  int e = blockIdx.x * 256 + threadIdx.x;
  if (e >= n) return;
  uint32_t f0 = 0u, f1 = (uint32_t)layer;
  tf_block(0u, 42u, f0, f1);
  uint32_t s0 = 0u, s1 = 1u;
  tf_block(f0, f1, s0, s1);
  uint32_t x0 = 0u, x1 = (uint32_t)e;
  tf_block(s0, s1, x0, x1);
  uint32_t bits = x0 ^ x1;
  idxb[e] = (int)(bits & (uint32_t)mask);
}

// ---------------------------------------------------------------- GEMM 128x128 (XCD-swizzled 1D grid)
// C[m,n] = act( sum_k A[m,k]*W[n,k] + bias[n] + (HASR ? R[m,n] : 0) )
// grid = ntx*nty blocks; nty divisible by 8. xcd = blk&7 owns row-tile band.
// CONV=1: logical A[r][k] = x[bbase + ((t-1+w)&Lmask)][k&511], w=k>>9 (K=1536).
// LDS skew (granularity 4): phys(c) = c + ((c>>5)<<2), row stride 140.
__device__ __forceinline__ float gelu_f(float v) {
  return 0.5f * v * (1.0f + erff(v * 0.7071067811865476f));
}

template <int ACT, int HASR, int CONV>
__global__ __launch_bounds__(256, 2) void gemm128(
    const float* __restrict__ A, const float* __restrict__ W,
    const float* __restrict__ bias, const float* Rres, float* C,
    int N, int K, int Lmask, int ntx, int nty) {
  __shared__ float As[16][140];
  __shared__ float Ws[16][140];
  const int tid = threadIdx.x;
  const int blk = blockIdx.x;
  const int xcd = blk & 7;
  const int j = blk >> 3;
  const int jr = j / ntx;
  const int row_t = xcd * (nty >> 3) + jr;
  const int col_t = j - jr * ntx;
  const int row0 = row_t * 128, col0 = col_t * 128;

  const int ar = tid >> 1;        // 0..127
  const int ac = (tid & 1) << 3;  // 0 / 8
  const int arp = ar + ((ar >> 5) << 2);        // skewed store col
  const int tx = tid & 15, ty = tid >> 4;
  const int wcol = tx * 8 + ((tx >> 2) << 2);   // skewed read col (W frag)
  const int acol = ty * 8 + ((ty >> 2) << 2);   // skewed read col (A frag)
  const int arow = row0 + ar;
  const float* Wp = W + (size_t)(col0 + ar) * K + ac;
  const float* Ap = A + (size_t)arow * K + ac;
  int tcv = 0, bbase = 0;
  if (CONV) { tcv = arow & Lmask; bbase = arow & ~Lmask; }
  float4 ra0, ra1, rw0, rw1;
  float acc[8][8] = {};
  const int T = K >> 4;

  {
    const float* ap;
    if (CONV) {
      int src = bbase | ((tcv - 1) & Lmask);  // k0=0 -> w=0
      ap = A + (size_t)src * 512 + ac;
    } else {
      ap = Ap;
    }
    ra0 = *(const float4*)(ap);
    ra1 = *(const float4*)(ap + 4);
    rw0 = *(const float4*)(Wp);
    rw1 = *(const float4*)(Wp + 4);
  }

  for (int it = 0; it < T; ++it) {
#pragma unroll
    for (int q = 0; q < 4; q++) {
      As[ac + q][arp] = ((float*)&ra0)[q];
      As[ac + 4 + q][arp] = ((float*)&ra1)[q];
      Ws[ac + q][arp] = ((float*)&rw0)[q];
      Ws[ac + 4 + q][arp] = ((float*)&rw1)[q];
    }
    __syncthreads();
    if (it + 1 < T) {
      const int k0 = (it + 1) << 4;
      const float* ap;
      if (CONV) {
        int w = k0 >> 9;
        int src = bbase | ((tcv - 1 + w) & Lmask);
        ap = A + (size_t)src * 512 + ((k0 & 511) + ac);
      } else {
        ap = Ap + k0;
      }
      ra0 = *(const float4*)(ap);
      ra1 = *(const float4*)(ap + 4);
      rw0 = *(const float4*)(Wp + k0);
      rw1 = *(const float4*)(Wp + k0 + 4);
    }
#pragma unroll
    for (int k = 0; k < 16; k++) {
      float av[8], wv[8];
      *(float4*)(av) = *(const float4*)&As[k][acol];
      *(float4*)(av + 4) = *(const float4*)&As[k][acol + 4];
      *(float4*)(wv) = *(const float4*)&Ws[k][wcol];
      *(float4*)(wv + 4) = *(const float4*)&Ws[k][wcol + 4];
#pragma unroll
      for (int i = 0; i < 8; i++)
#pragma unroll
        for (int q = 0; q < 8; q++) acc[i][q] += av[i] * wv[q];
    }
    __syncthreads();
  }

#pragma unroll
  for (int i = 0; i < 8; i++) {
    const int m = row0 + ty * 8 + i;
    const int c0 = col0 + tx * 8;
    float vout[8];
#pragma unroll
    for (int q = 0; q < 8; q++) {
      float v = acc[i][q] + bias[c0 + q];
      if (HASR) v += Rres[(size_t)m * N + c0 + q];
      if (ACT == 1) v = gelu_f(v);
      vout[q] = v;
    }
    *(float4*)(C + (size_t)m * N + c0) = *(float4*)(vout);
    *(float4*)(C + (size_t)m * N + c0 + 4) = *(float4*)(vout + 4);
  }
}

// ---------------------------------------------------------------- token conv + pos embed
__global__ void tokpe_kernel(const float* __restrict__ xe,
                             const float* __restrict__ w,
                             float* __restrict__ out, int S) {
  int gid = blockIdx.x * 256 + threadIdx.x;  // B*S*512
  int o = gid & 511;
  int bt = gid >> 9;
  int t = bt % S, b = bt / S;
  float acc = 0.f;
#pragma unroll
  for (int ww = 0; ww < 3; ww++) {
    int tt = t - 1 + ww;
    tt = (tt < 0) ? tt + S : (tt >= S ? tt - S : tt);
    const float* xr = xe + ((size_t)(b * S + tt)) * 7;
#pragma unroll
    for (int i = 0; i < 7; i++) acc += xr[i] * w[o * 21 + i * 3 + ww];
  }
  int i2 = o >> 1;
  float dv = expf((float)(2 * i2) * (-9.210340371976184f / 512.0f));
  float ang = (float)t * dv;
  acc += (o & 1) ? cosf(ang) : sinf(ang);
  out[gid] = acc;
}

// ---------------------------------------------------------------- conv weight pack
__global__ void packw_kernel(const float* __restrict__ dw, float* __restrict__ wp) {
  int gid = blockIdx.x * 256 + threadIdx.x;  // 512*1536
  int o = gid / 1536;
  int kk = gid - o * 1536;
  int ww = kk / 512;
  int c = kk - ww * 512;
  wp[gid] = dw[((size_t)o * 512 + c) * 3 + ww];
}

// ---------------------------------------------------------------- M score, all batches (b = blk&7 for XCD locality)
__global__ __launch_bounds__(256) void mscore_kernel(
    const float* __restrict__ Q, const float* __restrict__ Kb,
    const int* __restrict__ idxb, float* __restrict__ Mout, int L, int U) {
  int i = blockIdx.x;
  int b = i & 7;
  int j = i >> 3;
  int chunks = L >> 8;
  int h = j / chunks;
  int c = j - h * chunks;
  int t = c * 256 + threadIdx.x;
  const float4* qr = (const float4*)(Q + ((size_t)(b * L + t)) * DMODEL + h * HD);
  float4 qv[16];
#pragma unroll
  for (int ii = 0; ii < 16; ii++) qv[ii] = qr[ii];
  float mx = -3.4e38f, sm = 0.f;
  for (int jj = 0; jj < U; jj++) {
    int kr = idxb[t * U + jj];
    const float4* kp =
        (const float4*)(Kb + ((size_t)(b * L + kr)) * DMODEL + h * HD);
    float dot = 0.f;
#pragma unroll
    for (int ii = 0; ii < 16; ii++) {
      float4 kv = kp[ii];
      dot += qv[ii].x * kv.x + qv[ii].y * kv.y + qv[ii].z * kv.z + qv[ii].w * kv.w;
    }
    mx = fmaxf(mx, dot);
    sm += dot;
  }
  Mout[(size_t)(b * 8 + h) * L + t] = mx - sm / (float)L;
}

// ---------------------------------------------------------------- top-k (per b,h), register-resident
__global__ __launch_bounds__(256) void topk_kernel(const float* __restrict__ Mv,
                                                   int* __restrict__ topb, int L,
                                                   int u) {
  __shared__ float wv_s[4];
  __shared__ int wi_s[4];
  __shared__ int best_s;
  int bh = blockIdx.x, tid = threadIdx.x;
  int lane = tid & 63, w = tid >> 6;
  int cnt = L >> 8;  // 8 / 4 / 2
  float lv[8];
  for (int i = 0; i < cnt; i++) lv[i] = Mv[(size_t)bh * L + i * 256 + tid];
  for (int r = 0; r < u; r++) {
    float bv = -3.4e38f;
    int bi = 0x7fffffff;
    for (int i = 0; i < cnt; i++) {
      if (lv[i] > bv) { bv = lv[i]; bi = i * 256 + tid; }
    }
    for (int s = 32; s > 0; s >>= 1) {
      float ov = __shfl_down(bv, s);
      int oi = __shfl_down(bi, s);
      if (ov > bv || (ov == bv && oi < bi)) { bv = ov; bi = oi; }
    }
    if (lane == 0) { wv_s[w] = bv; wi_s[w] = bi; }
    __syncthreads();
    if (tid == 0) {
      float fv = wv_s[0];
      int fi = wi_s[0];
      for (int q = 1; q < 4; q++) {
        if (wv_s[q] > fv || (wv_s[q] == fv && wi_s[q] < fi)) {
          fv = wv_s[q];
          fi = wi_s[q];
        }
      }
      best_s = fi;
      topb[bh * u + r] = fi;
    }
    __syncthreads();
    int win = best_s;
    if ((win & 255) == tid) lv[win >> 8] = -3.4e38f;
  }
}

// ---------------------------------------------------------------- gather selected q rows
__global__ void gatherq_kernel(const float* __restrict__ Q,
                               const int* __restrict__ topb,
                               float* __restrict__ qsel, int L, int u) {
  int i = blockIdx.x;  // (b*8+h)*u + r
  int bh = i / u;
  int b = bh >> 3, h = bh & 7;
  int t = topb[i];
  qsel[i * HD + threadIdx.x] =
      Q[((size_t)(b * L + t)) * DMODEL + h * HD + threadIdx.x];
}

// ---------------------------------------------------------------- mean of x rows per batch (partial)
__global__ __launch_bounds__(256) void xmean_kernel(const float* __restrict__ x,
                                                    float* __restrict__ psumx,
                                                    int L) {
  int i = blockIdx.x;  // 64: b*8+g
  int b = i >> 3, g = i & 7;
  int rows = L >> 3;
  int tid = threadIdx.x;
  const float* base = x + ((size_t)b * L + (size_t)g * rows) * DMODEL;
  float s0 = 0.f, s1 = 0.f;
  for (int t = 0; t < rows; t++) {
    s0 += base[(size_t)t * DMODEL + tid];
    s1 += base[(size_t)t * DMODEL + tid + 256];
  }
  psumx[i * DMODEL + tid] = s0;
  psumx[i * DMODEL + tid + 256] = s1;
}

// mv = xmean@Wv^T + bv ; mvWo = mv@Wo^T + bo
__global__ __launch_bounds__(256) void mvmake_kernel(
    const float* __restrict__ psumx, const float* __restrict__ Wv,
    const float* __restrict__ bv, const float* __restrict__ Wo,
    const float* __restrict__ bo, float* __restrict__ mvg,
    float* __restrict__ mvWog, int L) {
  __shared__ float xm[512];
  __shared__ float mvs[512];
  int b = blockIdx.x, tid = threadIdx.x;
  float inv = 1.0f / (float)L;
  for (int nn = 0; nn < 2; nn++) {
    int c = tid + nn * 256;
    float s = 0.f;
    for (int g = 0; g < 8; g++) s += psumx[(b * 8 + g) * DMODEL + c];
    xm[c] = s * inv;
  }
  __syncthreads();
  for (int nn = 0; nn < 2; nn++) {
    int n = tid + nn * 256;
    const float* wr = Wv + (size_t)n * 512;
    float s = bv[n];
    for (int k = 0; k < 512; k += 4) {
      float4 w4 = *(const float4*)(wr + k);
      s += xm[k] * w4.x + xm[k + 1] * w4.y + xm[k + 2] * w4.z + xm[k + 3] * w4.w;
    }
    mvs[n] = s;
    mvg[b * DMODEL + n] = s;
  }
  __syncthreads();
  for (int nn = 0; nn < 2; nn++) {
    int n = tid + nn * 256;
    const float* wr = Wo + (size_t)n * 512;
    float s = bo[n];
    for (int k = 0; k < 512; k += 4) {
      float4 w4 = *(const float4*)(wr + k);
      s += mvs[k] * w4.x + mvs[k + 1] * w4.y + mvs[k + 2] * w4.z +
           mvs[k + 3] * w4.w;
    }
    mvWog[b * DMODEL + n] = s;
  }
}

// x1 = x + mvWo[b] (broadcast)
__global__ void x1bcast_kernel(const float* __restrict__ x,
                               const float* __restrict__ mvWog,
                               float* __restrict__ x1, int L) {
  int gid = blockIdx.x * 256 + threadIdx.x;  // BL*512
  int c = gid & 511;
  int r = gid >> 9;
  int b = r / L;
  x1[gid] = x[gid] + mvWog[b * DMODEL + c];
}

// ---------------------------------------------------------------- flash attention for selected rows
// One block per (b,h). Wave w owns queries qi = 4k + w. Online softmax.
// d = attn_out - mv_h -> dsel
__global__ __launch_bounds__(256) void attnflash_kernel(
    const float* __restrict__ qsel, const float* __restrict__ Kb,
    const float* __restrict__ Vb, const float* __restrict__ mvg,
    float* __restrict__ dsel, int L, int u) {
  __shared__ float qs[24][64];
  __shared__ float Kt[64][68];   // transposed K tile: Kt[d][j]
  __shared__ float Ps[24][68];   // P row per query
  int bh = blockIdx.x;           // b*8+h
  int b = bh >> 3, h = bh & 7;
  int tid = threadIdx.x;
  int lane = tid & 63;
  int w = tid >> 6;
  // stage all selected q rows (coalesced from qsel)
  for (int i = tid; i < u * 64; i += 256)
    qs[i >> 6][i & 63] = qsel[(size_t)bh * u * 64 + i];
  float m[6], l[6], O[6];
#pragma unroll
  for (int k = 0; k < 6; k++) { m[k] = -3.4e38f; l[k] = 0.f; O[k] = 0.f; }
  const float* Kbase = Kb + (size_t)b * L * DMODEL + h * HD;
  const float* Vbase = Vb + (size_t)b * L * DMODEL + h * HD;
  const int jrow = tid & 63;   // staging row
  const int dch = (tid >> 6) << 4;  // staging d-chunk base (0,16,32,48)
  for (int j0 = 0; j0 < L; j0 += 64) {
    __syncthreads();  // protect Kt (and qs on first iter) from in-flight readers
    const float* kr = Kbase + (size_t)(j0 + jrow) * DMODEL + dch;
    float4 k0 = *(const float4*)(kr);
    float4 k1 = *(const float4*)(kr + 4);
    float4 k2 = *(const float4*)(kr + 8);
    float4 k3 = *(const float4*)(kr + 12);
#pragma unroll
    for (int q = 0; q < 4; q++) {
      Kt[dch + q][jrow] = ((float*)&k0)[q];
      Kt[dch + 4 + q][jrow] = ((float*)&k1)[q];
      Kt[dch + 8 + q][jrow] = ((float*)&k2)[q];
      Kt[dch + 12 + q][jrow] = ((float*)&k3)[q];
    }
    __syncthreads();
    // QK + online softmax (wave-local)
#pragma unroll
    for (int k = 0; k < 6; k++) {
      int qi = 4 * k + w;
      if (qi >= u) break;
      float s = 0.f;
#pragma unroll
      for (int d = 0; d < 64; d++) s += qs[qi][d] * Kt[d][lane];
      s *= 0.125f;
      float mx = s;
#pragma unroll
      for (int off = 32; off > 0; off >>= 1)
        mx = fmaxf(mx, __shfl_down(mx, off));
      mx = __shfl(mx, 0);
      float mnew = fmaxf(m[k], mx);
      float p = expf(s - mnew);
      float ps = p;
#pragma unroll
      for (int off = 32; off > 0; off >>= 1) ps += __shfl_down(ps, off);
      ps = __shfl(ps, 0);
      float alpha = expf(m[k] - mnew);
      l[k] = l[k] * alpha + ps;
      m[k] = mnew;
      O[k] *= alpha;
      Ps[qi][lane] = p;
    }
    // PV: lane = d; V read direct from global (coalesced, L1-hot across waves)
    for (int j = 0; j < 64; j += 4) {
      float v0 = Vbase[(size_t)(j0 + j) * DMODEL + lane];
      float v1 = Vbase[(size_t)(j0 + j + 1) * DMODEL + lane];
      float v2 = Vbase[(size_t)(j0 + j + 2) * DMODEL + lane];
      float v3 = Vbase[(size_t)(j0 + j + 3) * DMODEL + lane];
#pragma unroll
      for (int k = 0; k < 6; k++) {
        int qi = 4 * k + w;
        if (qi >= u) break;
        O[k] += Ps[qi][j] * v0 + Ps[qi][j + 1] * v1 + Ps[qi][j + 2] * v2 +
                Ps[qi][j + 3] * v3;
      }
    }
  }
#pragma unroll
  for (int k = 0; k < 6; k++) {
    int qi = 4 * k + w;
    if (qi < u)
      dsel[(size_t)(bh * u + qi) * HD + lane] =
          O[k] / l[k] - mvg[b * DMODEL + h * HD + lane];
  }
}

// x1[row] += d @ Wo[:, h*64:(h+1)*64]^T  (scatter, atomic)
__global__ __launch_bounds__(256) void deltaWo_kernel(
    const float* __restrict__ dsel, const int* __restrict__ topb,
    const float* __restrict__ Wo, float* x1, int L, int u) {
  __shared__ float ds[64];
  int sel = blockIdx.x;  // (b*8+h)*u + r
  int bh = sel / u;
  int b = bh >> 3, h = bh & 7;
  int t = topb[sel];
  int tid = threadIdx.x;
  if (tid < 64) ds[tid] = dsel[sel * HD + tid];
  __syncthreads();
  float* row = x1 + ((size_t)(b * L + t)) * DMODEL;
  for (int nn = 0; nn < 2; nn++) {
    int n = tid + nn * 256;
    const float* wr = Wo + (size_t)n * 512 + h * HD;
    float a = 0.f;
#pragma unroll
    for (int k = 0; k < 64; k += 4) {
      float4 w4 = *(const float4*)(wr + k);
      a += ds[k] * w4.x + ds[k + 1] * w4.y + ds[k + 2] * w4.z + ds[k + 3] * w4.w;
    }
    atomicAdd(row + n, a);
  }
}

// ---------------------------------------------------------------- layernorm (512 cols)
__global__ __launch_bounds__(256) void ln_kernel(const float* __restrict__ X,
                                                 const float* __restrict__ g,
                                                 const float* __restrict__ bta,
                                                 float* __restrict__ Y) {
  __shared__ float red[256];
  int row = blockIdx.x, tid = threadIdx.x;
  size_t base = (size_t)row * DMODEL;
  float x0 = X[base + tid], x1 = X[base + tid + 256];
  red[tid] = x0 + x1;
  __syncthreads();
  for (int s = 128; s > 0; s >>= 1) {
    if (tid < s) red[tid] += red[tid + s];
    __syncthreads();
  }
  float mean = red[0] * (1.0f / 512.0f);
  __syncthreads();
  float d0 = x0 - mean, d1 = x1 - mean;
  red[tid] = d0 * d0 + d1 * d1;
  __syncthreads();
  for (int s = 128; s > 0; s >>= 1) {
    if (tid < s) red[tid] += red[tid + s];
    __syncthreads();
  }
  float inv = 1.0f / sqrtf(red[0] * (1.0f / 512.0f) + 1e-5f);
  Y[base + tid] = d0 * inv * g[tid] + bta[tid];
  Y[base + tid + 256] = d1 * inv * g[tid + 256] + bta[tid + 256];
}

// ---------------------------------------------------------------- BN stats + pool
__global__ __launch_bounds__(256) void bnpart_kernel(const float* __restrict__ z,
                                                     float* __restrict__ psum,
                                                     float* __restrict__ psq,
                                                     int rowsPer) {
  int blk = blockIdx.x, tid = threadIdx.x;
  size_t r0 = (size_t)blk * rowsPer;
  float s0 = 0, q0 = 0, s1 = 0, q1 = 0;
  for (int r = 0; r < rowsPer; r++) {
    const float* zp = z + (r0 + r) * DMODEL;
    float a = zp[tid];
    s0 += a; q0 += a * a;
    float c = zp[tid + 256];
    s1 += c; q1 += c * c;
  }
  psum[blk * DMODEL + tid] = s0;
  psum[blk * DMODEL + tid + 256] = s1;
  psq[blk * DMODEL + tid] = q0;
  psq[blk * DMODEL + tid + 256] = q1;
}

__global__ void bnfin_kernel(const float* __restrict__ psum,
                             const float* __restrict__ psq, float* __restrict__ mu,
                             float* __restrict__ var, int nb, int Rtot) {
  int c = blockIdx.x * 256 + threadIdx.x;
  float s = 0, q = 0;
  for (int b = 0; b < nb; b++) {
    s += psum[b * DMODEL + c];
    q += psq[b * DMODEL + c];
  }
  float m = s / (float)Rtot;
  mu[c] = m;
  var[c] = fmaxf(q / (float)Rtot - m * m, 0.f);
}

__global__ void bnpool_kernel(const float* __restrict__ z,
                              const float* __restrict__ mu,
                              const float* __restrict__ var,
                              const float* __restrict__ g,
                              const float* __restrict__ bta,
                              float* __restrict__ out, int L) {
  int gid = blockIdx.x * 256 + threadIdx.x;  // B*(L/2)*512
  int c = gid & 511;
  int bt = gid >> 9;
  int L2 = L >> 1;
  int t2 = bt % L2, b = bt / L2;
  float m = mu[c];
  float inv = 1.0f / sqrtf(var[c] + 1e-5f);
  float gg = g[c], bb = bta[c];
  float best = -3.4e38f;
#pragma unroll
  for (int ww = 0; ww < 3; ww++) {
    int t = 2 * t2 - 1 + ww;
    if (t < 0 || t >= L) continue;
    float yv = (z[((size_t)(b * L + t)) * DMODEL + c] - m) * inv * gg + bb;
    yv = (yv > 0.f) ? yv : expm1f(yv);
    best = fmaxf(best, yv);
  }
  out[gid] = best;
}

// ---------------------------------------------------------------- final projection (512 -> 7)
__global__ __launch_bounds__(64) void end_kernel(const float* __restrict__ xn,
                                                 const float* __restrict__ ew,
                                                 const float* __restrict__ eb,
                                                 float* __restrict__ out) {
  __shared__ float xs[512];
  __shared__ float red[64];
  int row = blockIdx.x, tid = threadIdx.x;
#pragma unroll
  for (int i = 0; i < 8; i++) xs[tid + 64 * i] = xn[(size_t)row * DMODEL + tid + 64 * i];
  __syncthreads();
  for (int c = 0; c < 7; c++) {
    float p = 0.f;
    for (int d = tid; d < 512; d += 64) p += xs[d] * ew[c * DMODEL + d];
    red[tid] = p;
    __syncthreads();
    for (int s = 32; s > 0; s >>= 1) {
      if (tid < s) red[tid] += red[tid + s];
      __syncthreads();
    }
    if (tid == 0) out[row * 7 + c] = red[0] + eb[c];
    __syncthreads();
  }
}

// ---------------------------------------------------------------- host
extern "C" void kernel_launch(void* const* d_in, const int* in_sizes, int n_in,
                              void* d_out, int out_size, void* d_ws,
                              size_t ws_size, hipStream_t stream) {
  (void)in_sizes; (void)n_in; (void)out_size; (void)ws_size;
  const float* x_enc = (const float*)d_in[0];
  const float* tok_w = (const float*)d_in[1];
  const float* Wq = (const float*)d_in[2];
  const float* bq = (const float*)d_in[3];
  const float* Wk = (const float*)d_in[4];
  const float* bk = (const float*)d_in[5];
  const float* Wv = (const float*)d_in[6];
  const float* bv = (const float*)d_in[7];
  const float* Wo = (const float*)d_in[8];
  const float* bo = (const float*)d_in[9];
  const float* w1 = (const float*)d_in[10];
  const float* b1 = (const float*)d_in[11];
  const float* w2 = (const float*)d_in[12];
  const float* b2 = (const float*)d_in[13];
  const float* g1 = (const float*)d_in[14];
  const float* be1 = (const float*)d_in[15];
  const float* g2 = (const float*)d_in[16];
  const float* be2 = (const float*)d_in[17];
  const float* dw = (const float*)d_in[18];
  const float* db = (const float*)d_in[19];
  const float* bng = (const float*)d_in[20];
  const float* bnb = (const float*)d_in[21];
  const float* lnfg = (const float*)d_in[22];
  const float* lnfb = (const float*)d_in[23];
  const float* endw = (const float*)d_in[24];
  const float* endb = (const float*)d_in[25];
  float* out = (float*)d_out;
  char* ws = (char*)d_ws;

  // ---- arena (~105 MB) ----
  size_t o = 0;
  float* buf0 = (float*)(ws + o); o += (size_t)16384 * 512 * 4;  // x / CH(4096x2048)
  float* qbuf = (float*)(ws + o); o += (size_t)16384 * 512 * 4;  // Q / V / xa
  float* kbuf = (float*)(ws + o); o += (size_t)16384 * 512 * 4;  // K / x1=z
  float* wpack = (float*)(ws + o); o += (size_t)512 * 1536 * 4;
  float* Mb    = (float*)(ws + o); o += (size_t)64 * 2048 * 4;
  int*   idxb  = (int*)(ws + o);   o += (size_t)2048 * 24 * 4;
  int*   topb  = (int*)(ws + o);   o += 8192;
  float* qsel  = (float*)(ws + o); o += (size_t)64 * 24 * 64 * 4;
  float* dsel  = (float*)(ws + o); o += (size_t)64 * 24 * 64 * 4;
  float* mvg   = (float*)(ws + o); o += (size_t)8 * 512 * 4;
  float* mvWog = (float*)(ws + o); o += (size_t)8 * 512 * 4;
  float* psumx = (float*)(ws + o); o += (size_t)64 * 512 * 4;
  float* psum  = (float*)(ws + o); o += (size_t)128 * 512 * 4;
  float* psq   = (float*)(ws + o); o += (size_t)128 * 512 * 4;
  float* muv   = (float*)(ws + o); o += 2048;
  float* varv  = (float*)(ws + o); o += 2048;

  const int B = 8;
  const int S = 2048;
  tokpe_kernel<<<B * S * DMODEL / 256, 256, 0, stream>>>(x_enc, tok_w, buf0, S);

  int L = S;
  const int Uarr[3] = {24, 21, 21};  // 3*ceil(ln(L)) for 2048,1024,512
  for (int l = 0; l < 3; l++) {
    int U = Uarr[l];
    int u = Uarr[l];
    int BL = B * L;
    int nty = BL / 128;  // 128 / 64 / 32
    idx_kernel<<<(L * U + 255) / 256, 256, 0, stream>>>(idxb, L * U, l, L - 1);

    // Q, K (full batch)
    gemm128<0, 0, 0><<<4 * nty, 256, 0, stream>>>(
        buf0, Wq + (size_t)l * 262144, bq + l * 512, nullptr, qbuf, 512, 512, 0,
        4, nty);
    gemm128<0, 0, 0><<<4 * nty, 256, 0, stream>>>(
        buf0, Wk + (size_t)l * 262144, bk + l * 512, nullptr, kbuf, 512, 512, 0,
        4, nty);
    mscore_kernel<<<8 * 8 * L / 256, 256, 0, stream>>>(qbuf, kbuf, idxb, Mb, L, U);
    topk_kernel<<<64, 256, 0, stream>>>(Mb, topb, L, u);
    gatherq_kernel<<<64 * u, 64, 0, stream>>>(qbuf, topb, qsel, L, u);
    xmean_kernel<<<64, 256, 0, stream>>>(buf0, psumx, L);
    mvmake_kernel<<<8, 256, 0, stream>>>(psumx, Wv + (size_t)l * 262144,
                                         bv + l * 512, Wo + (size_t)l * 262144,
                                         bo + l * 512, mvg, mvWog, L);
    // V (overwrites Q buffer; qsel already gathered)
    gemm128<0, 0, 0><<<4 * nty, 256, 0, stream>>>(
        buf0, Wv + (size_t)l * 262144, bv + l * 512, nullptr, qbuf, 512, 512, 0,
        4, nty);
    attnflash_kernel<<<64, 256, 0, stream>>>(qsel, kbuf, qbuf, mvg, dsel, L, u);
    // x1 = x + mvWo (into kbuf, K no longer needed) ; += sparse delta@Wo
    x1bcast_kernel<<<BL * 512 / 256, 256, 0, stream>>>(buf0, mvWog, kbuf, L);
    deltaWo_kernel<<<64 * u, 256, 0, stream>>>(dsel, topb,
                                               Wo + (size_t)l * 262144, kbuf, L, u);
    // xa = LN1(x1) -> qbuf
    ln_kernel<<<BL, 256, 0, stream>>>(kbuf, g1 + l * 512, be1 + l * 512, qbuf);
    // FFN, 4096-row chunks; CH = buf0 (x dead). Residual is xa (qbuf)!
    for (int r0 = 0; r0 < BL; r0 += 4096) {
      gemm128<1, 0, 0><<<16 * 32, 256, 0, stream>>>(
          qbuf + (size_t)r0 * 512, w1 + (size_t)l * 2048 * 512, b1 + l * 2048,
          nullptr, buf0, 2048, 512, 0, 16, 32);
      gemm128<0, 1, 0><<<4 * 32, 256, 0, stream>>>(
          buf0, w2 + (size_t)l * 512 * 2048, b2 + l * 512,
          qbuf + (size_t)r0 * 512, kbuf + (size_t)r0 * 512, 512, 2048, 0, 4, 32);
    }
    // x = LN2(z) -> buf0
    ln_kernel<<<BL, 256, 0, stream>>>(kbuf, g2 + l * 512, be2 + l * 512, buf0);

    if (l < 2) {
      packw_kernel<<<512 * 1536 / 256, 256, 0, stream>>>(
          dw + (size_t)l * 512 * 512 * 3, wpack);
      gemm128<0, 0, 1><<<4 * nty, 256, 0, stream>>>(
          buf0, wpack, db + l * 512, nullptr, kbuf, 512, 1536, L - 1, 4, nty);
      int nb = BL / 128;
      bnpart_kernel<<<nb, 256, 0, stream>>>(kbuf, psum, psq, 128);
      bnfin_kernel<<<2, 256, 0, stream>>>(psum, psq, muv, varv, nb, BL);
      bnpool_kernel<<<(BL / 2) * 512 / 256, 256, 0, stream>>>(
          kbuf, muv, varv, bng + l * 512, bnb + l * 512, buf0, L);
      L >>= 1;
    }
  }
  int BL = B * L;  // 4096
  ln_kernel<<<BL, 256, 0, stream>>>(buf0, lnfg, lnfb, qbuf);
  end_kernel<<<BL, 64, 0, stream>>>(qbuf, endw, endb, out);
}

// Round 11
// 4792.567 us; speedup vs baseline: 1.1426x; 1.1426x over previous
//
#include <hip/hip_runtime.h>
#include <cstdint>
#include <cstddef>

#define DMODEL 512
#define NHEAD 8
#define HD 64

// ---------------------------------------------------------------- threefry
__device__ __forceinline__ uint32_t rotl32(uint32_t x, int r) {
  return (x << r) | (x >> (32 - r));
}

__device__ __forceinline__ void tf_block(uint32_t k0, uint32_t k1,
                                         uint32_t& x0, uint32_t& x1) {
  uint32_t ks0 = k0, ks1 = k1, ks2 = k0 ^ k1 ^ 0x1BD11BDAu;
  x0 += ks0; x1 += ks1;
  x0 += x1; x1 = rotl32(x1, 13); x1 ^= x0;
  x0 += x1; x1 = rotl32(x1, 15); x1 ^= x0;
  x0 += x1; x1 = rotl32(x1, 26); x1 ^= x0;
  x0 += x1; x1 = rotl32(x1, 6);  x1 ^= x0;
  x0 += ks1; x1 += ks2 + 1u;
  x0 += x1; x1 = rotl32(x1, 17); x1 ^= x0;
  x0 += x1; x1 = rotl32(x1, 29); x1 ^= x0;
  x0 += x1; x1 = rotl32(x1, 16); x1 ^= x0;
  x0 += x1; x1 = rotl32(x1, 24); x1 ^= x0;
  x0 += ks2; x1 += ks0 + 2u;
  x0 += x1; x1 = rotl32(x1, 13); x1 ^= x0;
  x0 += x1; x1 = rotl32(x1, 15); x1 ^= x0;
  x0 += x1; x1 = rotl32(x1, 26); x1 ^= x0;
  x0 += x1; x1 = rotl32(x1, 6);  x1 ^= x0;
  x0 += ks0; x1 += ks1 + 3u;
  x0 += x1; x1 = rotl32(x1, 17); x1 ^= x0;
  x0 += x1; x1 = rotl32(x1, 29); x1 ^= x0;
  x0 += x1; x1 = rotl32(x1, 16); x1 ^= x0;
  x0 += x1; x1 = rotl32(x1, 24); x1 ^= x0;
  x0 += ks1; x1 += ks2 + 4u;
  x0 += x1; x1 = rotl32(x1, 13); x1 ^= x0;
  x0 += x1; x1 = rotl32(x1, 15); x1 ^= x0;
  x0 += x1; x1 = rotl32(x1, 26); x1 ^= x0;
  x0 += x1; x1 = rotl32(x1, 6);  x1 ^= x0;
  x0 += ks2; x1 += ks0 + 5u;
}

__global__ void idx_kernel(int* __restrict__ idxb, int n, int layer, int mask) {
  int e = blockIdx.x * 256 + threadIdx.x;
  if (e >= n) return;
  uint32_t f0 = 0u, f1 = (uint32_t)layer;
  tf_block(0u, 42u, f0, f1);
  uint32_t s0 = 0u, s1 = 1u;
  tf_block(f0, f1, s0, s1);
  uint32_t x0 = 0u, x1 = (uint32_t)e;
  tf_block(s0, s1, x0, x1);
  uint32_t bits = x0 ^ x1;
  idxb[e] = (int)(bits & (uint32_t)mask);
}

// ---------------------------------------------------------------- GEMM 128x128 (XCD-swizzled 1D grid)
__device__ __forceinline__ float gelu_f(float v) {
  return 0.5f * v * (1.0f + erff(v * 0.7071067811865476f));
}

template <int ACT, int HASR, int CONV>
__global__ __launch_bounds__(256, 2) void gemm128(
    const float* __restrict__ A, const float* __restrict__ W,
    const float* __restrict__ bias, const float* Rres, float* C,
    int N, int K, int Lmask, int ntx, int nty) {
  __shared__ float As[16][140];
  __shared__ float Ws[16][140];
  const int tid = threadIdx.x;
  const int blk = blockIdx.x;
  const int xcd = blk & 7;
  const int j = blk >> 3;
  const int jr = j / ntx;
  const int row_t = xcd * (nty >> 3) + jr;
  const int col_t = j - jr * ntx;
  const int row0 = row_t * 128, col0 = col_t * 128;

  const int ar = tid >> 1;        // 0..127
  const int ac = (tid & 1) << 3;  // 0 / 8
  const int arp = ar + ((ar >> 5) << 2);        // skewed store col
  const int tx = tid & 15, ty = tid >> 4;
  const int wcol = tx * 8 + ((tx >> 2) << 2);   // skewed read col (W frag)
  const int acol = ty * 8 + ((ty >> 2) << 2);   // skewed read col (A frag)
  const int arow = row0 + ar;
  const float* Wp = W + (size_t)(col0 + ar) * K + ac;
  const float* Ap = A + (size_t)arow * K + ac;
  int tcv = 0, bbase = 0;
  if (CONV) { tcv = arow & Lmask; bbase = arow & ~Lmask; }
  float4 ra0, ra1, rw0, rw1;
  float acc[8][8] = {};
  const int T = K >> 4;

  {
    const float* ap;
    if (CONV) {
      int src = bbase | ((tcv - 1) & Lmask);  // k0=0 -> w=0
      ap = A + (size_t)src * 512 + ac;
    } else {
      ap = Ap;
    }
    ra0 = *(const float4*)(ap);
    ra1 = *(const float4*)(ap + 4);
    rw0 = *(const float4*)(Wp);
    rw1 = *(const float4*)(Wp + 4);
  }

  for (int it = 0; it < T; ++it) {
#pragma unroll
    for (int q = 0; q < 4; q++) {
      As[ac + q][arp] = ((float*)&ra0)[q];
      As[ac + 4 + q][arp] = ((float*)&ra1)[q];
      Ws[ac + q][arp] = ((float*)&rw0)[q];
      Ws[ac + 4 + q][arp] = ((float*)&rw1)[q];
    }
    __syncthreads();
    if (it + 1 < T) {
      const int k0 = (it + 1) << 4;
      const float* ap;
      if (CONV) {
        int w = k0 >> 9;
        int src = bbase | ((tcv - 1 + w) & Lmask);
        ap = A + (size_t)src * 512 + ((k0 & 511) + ac);
      } else {
        ap = Ap + k0;
      }
      ra0 = *(const float4*)(ap);
      ra1 = *(const float4*)(ap + 4);
      rw0 = *(const float4*)(Wp + k0);
      rw1 = *(const float4*)(Wp + k0 + 4);
    }
#pragma unroll
    for (int k = 0; k < 16; k++) {
      float av[8], wv[8];
      *(float4*)(av) = *(const float4*)&As[k][acol];
      *(float4*)(av + 4) = *(const float4*)&As[k][acol + 4];
      *(float4*)(wv) = *(const float4*)&Ws[k][wcol];
      *(float4*)(wv + 4) = *(const float4*)&Ws[k][wcol + 4];
#pragma unroll
      for (int i = 0; i < 8; i++)
#pragma unroll
        for (int q = 0; q < 8; q++) acc[i][q] += av[i] * wv[q];
    }
    __syncthreads();
  }

#pragma unroll
  for (int i = 0; i < 8; i++) {
    const int m = row0 + ty * 8 + i;
    const int c0 = col0 + tx * 8;
    float vout[8];
#pragma unroll
    for (int q = 0; q < 8; q++) {
      float v = acc[i][q] + bias[c0 + q];
      if (HASR) v += Rres[(size_t)m * N + c0 + q];
      if (ACT == 1) v = gelu_f(v);
      vout[q] = v;
    }
    *(float4*)(C + (size_t)m * N + c0) = *(float4*)(vout);
    *(float4*)(C + (size_t)m * N + c0 + 4) = *(float4*)(vout + 4);
  }
}

// ---------------------------------------------------------------- token conv + pos embed
__global__ void tokpe_kernel(const float* __restrict__ xe,
                             const float* __restrict__ w,
                             float* __restrict__ out, int S) {
  int gid = blockIdx.x * 256 + threadIdx.x;  // B*S*512
  int o = gid & 511;
  int bt = gid >> 9;
  int t = bt % S, b = bt / S;
  float acc = 0.f;
#pragma unroll
  for (int ww = 0; ww < 3; ww++) {
    int tt = t - 1 + ww;
    tt = (tt < 0) ? tt + S : (tt >= S ? tt - S : tt);
    const float* xr = xe + ((size_t)(b * S + tt)) * 7;
#pragma unroll
    for (int i = 0; i < 7; i++) acc += xr[i] * w[o * 21 + i * 3 + ww];
  }
  int i2 = o >> 1;
  float dv = expf((float)(2 * i2) * (-9.210340371976184f / 512.0f));
  float ang = (float)t * dv;
  acc += (o & 1) ? cosf(ang) : sinf(ang);
  out[gid] = acc;
}

// ---------------------------------------------------------------- conv weight pack
__global__ void packw_kernel(const float* __restrict__ dw, float* __restrict__ wp) {
  int gid = blockIdx.x * 256 + threadIdx.x;  // 512*1536
  int o = gid / 1536;
  int kk = gid - o * 1536;
  int ww = kk / 512;
  int c = kk - ww * 512;
  wp[gid] = dw[((size_t)o * 512 + c) * 3 + ww];
}

// ---------------------------------------------------------------- M score, all batches (b = blk&7 for XCD locality)
__global__ __launch_bounds__(256) void mscore_kernel(
    const float* __restrict__ Q, const float* __restrict__ Kb,
    const int* __restrict__ idxb, float* __restrict__ Mout, int L, int U) {
  int i = blockIdx.x;
  int b = i & 7;
  int j = i >> 3;
  int chunks = L >> 8;
  int h = j / chunks;
  int c = j - h * chunks;
  int t = c * 256 + threadIdx.x;
  const float4* qr = (const float4*)(Q + ((size_t)(b * L + t)) * DMODEL + h * HD);
  float4 qv[16];
#pragma unroll
  for (int ii = 0; ii < 16; ii++) qv[ii] = qr[ii];
  float mx = -3.4e38f, sm = 0.f;
  for (int jj = 0; jj < U; jj++) {
    int kr = idxb[t * U + jj];
    const float4* kp =
        (const float4*)(Kb + ((size_t)(b * L + kr)) * DMODEL + h * HD);
    float dot = 0.f;
#pragma unroll
    for (int ii = 0; ii < 16; ii++) {
      float4 kv = kp[ii];
      dot += qv[ii].x * kv.x + qv[ii].y * kv.y + qv[ii].z * kv.z + qv[ii].w * kv.w;
    }
    mx = fmaxf(mx, dot);
    sm += dot;
  }
  Mout[(size_t)(b * 8 + h) * L + t] = mx - sm / (float)L;
}

// ---------------------------------------------------------------- top-k (per b,h), register-resident
__global__ __launch_bounds__(256) void topk_kernel(const float* __restrict__ Mv,
                                                   int* __restrict__ topb, int L,
                                                   int u) {
  __shared__ float wv_s[4];
  __shared__ int wi_s[4];
  __shared__ int best_s;
  int bh = blockIdx.x, tid = threadIdx.x;
  int lane = tid & 63, w = tid >> 6;
  int cnt = L >> 8;  // 8 / 4 / 2
  float lv[8];
  for (int i = 0; i < cnt; i++) lv[i] = Mv[(size_t)bh * L + i * 256 + tid];
  for (int r = 0; r < u; r++) {
    float bv = -3.4e38f;
    int bi = 0x7fffffff;
    for (int i = 0; i < cnt; i++) {
      if (lv[i] > bv) { bv = lv[i]; bi = i * 256 + tid; }
    }
    for (int s = 32; s > 0; s >>= 1) {
      float ov = __shfl_down(bv, s);
      int oi = __shfl_down(bi, s);
      if (ov > bv || (ov == bv && oi < bi)) { bv = ov; bi = oi; }
    }
    if (lane == 0) { wv_s[w] = bv; wi_s[w] = bi; }
    __syncthreads();
    if (tid == 0) {
      float fv = wv_s[0];
      int fi = wi_s[0];
      for (int q = 1; q < 4; q++) {
        if (wv_s[q] > fv || (wv_s[q] == fv && wi_s[q] < fi)) {
          fv = wv_s[q];
          fi = wi_s[q];
        }
      }
      best_s = fi;
      topb[bh * u + r] = fi;
    }
    __syncthreads();
    int win = best_s;
    if ((win & 255) == tid) lv[win >> 8] = -3.4e38f;
  }
}

// ---------------------------------------------------------------- gather selected q rows
__global__ void gatherq_kernel(const float* __restrict__ Q,
                               const int* __restrict__ topb,
                               float* __restrict__ qsel, int L, int u) {
  int i = blockIdx.x;  // (b*8+h)*u + r
  int bh = i / u;
  int b = bh >> 3, h = bh & 7;
  int t = topb[i];
  qsel[i * HD + threadIdx.x] =
      Q[((size_t)(b * L + t)) * DMODEL + h * HD + threadIdx.x];
}

// ---------------------------------------------------------------- mean of x rows per batch (partial)
__global__ __launch_bounds__(256) void xmean_kernel(const float* __restrict__ x,
                                                    float* __restrict__ psumx,
                                                    int L) {
  int i = blockIdx.x;  // 64: b*8+g
  int b = i >> 3, g = i & 7;
  int rows = L >> 3;
  int tid = threadIdx.x;
  const float* base = x + ((size_t)b * L + (size_t)g * rows) * DMODEL;
  float s0 = 0.f, s1 = 0.f;
  for (int t = 0; t < rows; t++) {
    s0 += base[(size_t)t * DMODEL + tid];
    s1 += base[(size_t)t * DMODEL + tid + 256];
  }
  psumx[i * DMODEL + tid] = s0;
  psumx[i * DMODEL + tid + 256] = s1;
}

// mv = xmean@Wv^T + bv ; mvWo = mv@Wo^T + bo
__global__ __launch_bounds__(256) void mvmake_kernel(
    const float* __restrict__ psumx, const float* __restrict__ Wv,
    const float* __restrict__ bv, const float* __restrict__ Wo,
    const float* __restrict__ bo, float* __restrict__ mvg,
    float* __restrict__ mvWog, int L) {
  __shared__ float xm[512];
  __shared__ float mvs[512];
  int b = blockIdx.x, tid = threadIdx.x;
  float inv = 1.0f / (float)L;
  for (int nn = 0; nn < 2; nn++) {
    int c = tid + nn * 256;
    float s = 0.f;
    for (int g = 0; g < 8; g++) s += psumx[(b * 8 + g) * DMODEL + c];
    xm[c] = s * inv;
  }
  __syncthreads();
  for (int nn = 0; nn < 2; nn++) {
    int n = tid + nn * 256;
    const float* wr = Wv + (size_t)n * 512;
    float s = bv[n];
    for (int k = 0; k < 512; k += 4) {
      float4 w4 = *(const float4*)(wr + k);
      s += xm[k] * w4.x + xm[k + 1] * w4.y + xm[k + 2] * w4.z + xm[k + 3] * w4.w;
    }
    mvs[n] = s;
    mvg[b * DMODEL + n] = s;
  }
  __syncthreads();
  for (int nn = 0; nn < 2; nn++) {
    int n = tid + nn * 256;
    const float* wr = Wo + (size_t)n * 512;
    float s = bo[n];
    for (int k = 0; k < 512; k += 4) {
      float4 w4 = *(const float4*)(wr + k);
      s += mvs[k] * w4.x + mvs[k + 1] * w4.y + mvs[k + 2] * w4.z +
           mvs[k + 3] * w4.w;
    }
    mvWog[b * DMODEL + n] = s;
  }
}

// x1 = x + mvWo[b] (broadcast)
__global__ void x1bcast_kernel(const float* __restrict__ x,
                               const float* __restrict__ mvWog,
                               float* __restrict__ x1, int L) {
  int gid = blockIdx.x * 256 + threadIdx.x;  // BL*512
  int c = gid & 511;
  int r = gid >> 9;
  int b = r / L;
  x1[gid] = x[gid] + mvWog[b * DMODEL + c];
}

// ---------------------------------------------------------------- chunked flash attention for selected rows
// Grid = 64*nchunk. Block (bh, c) processes keys [c*cs, (c+1)*cs), cs = L/nchunk.
// Emits per-chunk partials: pm, pl (uniform), pO (unnormalized O), p = (bh*nchunk+c)*u+qi.
__global__ __launch_bounds__(256) void attnflash_kernel(
    const float* __restrict__ qsel, const float* __restrict__ Kb,
    const float* __restrict__ Vb, float* __restrict__ pm,
    float* __restrict__ pl, float* __restrict__ pO, int L, int u, int nchunk) {
  __shared__ float qs[24][64];
  __shared__ float Kt[64][68];   // transposed K tile: Kt[d][j]
  __shared__ float Ps[24][68];   // P row per query (wave-local rows)
  int blk = blockIdx.x;          // bh*nchunk + c
  int bh = blk / nchunk;
  int c = blk - bh * nchunk;
  int b = bh >> 3, h = bh & 7;
  int cs = L / nchunk;
  int tid = threadIdx.x;
  int lane = tid & 63;
  int w = tid >> 6;
  for (int i = tid; i < u * 64; i += 256)
    qs[i >> 6][i & 63] = qsel[(size_t)bh * u * 64 + i];
  float m[6], l[6], O[6];
#pragma unroll
  for (int k = 0; k < 6; k++) { m[k] = -3.4e38f; l[k] = 0.f; O[k] = 0.f; }
  const float* Kbase = Kb + (size_t)b * L * DMODEL + h * HD;
  const float* Vbase = Vb + (size_t)b * L * DMODEL + h * HD;
  const int jrow = tid & 63;        // staging row
  const int dch = (tid >> 6) << 4;  // staging d-chunk base (0,16,32,48)
  for (int j0 = c * cs; j0 < (c + 1) * cs; j0 += 64) {
    __syncthreads();  // protect Kt (and qs on first iter)
    const float* kr = Kbase + (size_t)(j0 + jrow) * DMODEL + dch;
    float4 k0 = *(const float4*)(kr);
    float4 k1 = *(const float4*)(kr + 4);
    float4 k2 = *(const float4*)(kr + 8);
    float4 k3 = *(const float4*)(kr + 12);
#pragma unroll
    for (int q = 0; q < 4; q++) {
      Kt[dch + q][jrow] = ((float*)&k0)[q];
      Kt[dch + 4 + q][jrow] = ((float*)&k1)[q];
      Kt[dch + 8 + q][jrow] = ((float*)&k2)[q];
      Kt[dch + 12 + q][jrow] = ((float*)&k3)[q];
    }
    __syncthreads();
#pragma unroll
    for (int k = 0; k < 6; k++) {
      int qi = 4 * k + w;
      if (qi >= u) break;
      float s = 0.f;
#pragma unroll
      for (int d = 0; d < 64; d++) s += qs[qi][d] * Kt[d][lane];
      s *= 0.125f;
      float mx = s;
#pragma unroll
      for (int off = 32; off > 0; off >>= 1)
        mx = fmaxf(mx, __shfl_down(mx, off));
      mx = __shfl(mx, 0);
      float mnew = fmaxf(m[k], mx);
      float p = expf(s - mnew);
      float ps = p;
#pragma unroll
      for (int off = 32; off > 0; off >>= 1) ps += __shfl_down(ps, off);
      ps = __shfl(ps, 0);
      float alpha = expf(m[k] - mnew);
      l[k] = l[k] * alpha + ps;
      m[k] = mnew;
      O[k] *= alpha;
      Ps[qi][lane] = p;
    }
    for (int j = 0; j < 64; j += 4) {
      float v0 = Vbase[(size_t)(j0 + j) * DMODEL + lane];
      float v1 = Vbase[(size_t)(j0 + j + 1) * DMODEL + lane];
      float v2 = Vbase[(size_t)(j0 + j + 2) * DMODEL + lane];
      float v3 = Vbase[(size_t)(j0 + j + 3) * DMODEL + lane];
#pragma unroll
      for (int k = 0; k < 6; k++) {
        int qi = 4 * k + w;
        if (qi >= u) break;
        O[k] += Ps[qi][j] * v0 + Ps[qi][j + 1] * v1 + Ps[qi][j + 2] * v2 +
                Ps[qi][j + 3] * v3;
      }
    }
  }
#pragma unroll
  for (int k = 0; k < 6; k++) {
    int qi = 4 * k + w;
    if (qi < u) {
      int p = (bh * nchunk + c) * u + qi;
      if (lane == 0) { pm[p] = m[k]; pl[p] = l[k]; }
      pO[(size_t)p * 64 + lane] = O[k];
    }
  }
}

// combine chunk partials -> dsel = softmax-attention output - mv
__global__ __launch_bounds__(64) void attncomb_kernel(
    const float* __restrict__ pm, const float* __restrict__ pl,
    const float* __restrict__ pO, const float* __restrict__ mvg,
    float* __restrict__ dsel, int u, int nchunk) {
  int i = blockIdx.x;  // bh*u + qi
  int bh = i / u;
  int qi = i - bh * u;
  int b = bh >> 3, h = bh & 7;
  int d = threadIdx.x;
  float mstar = -3.4e38f;
  for (int c = 0; c < nchunk; c++)
    mstar = fmaxf(mstar, pm[(bh * nchunk + c) * u + qi]);
  float lstar = 0.f, O = 0.f;
  for (int c = 0; c < nchunk; c++) {
    int p = (bh * nchunk + c) * u + qi;
    float wgt = expf(pm[p] - mstar);
    lstar += wgt * pl[p];
    O += wgt * pO[(size_t)p * 64 + d];
  }
  dsel[(size_t)i * 64 + d] = O / lstar - mvg[b * DMODEL + h * HD + d];
}

// x1[row] += d @ Wo[:, h*64:(h+1)*64]^T  (scatter, atomic)
__global__ __launch_bounds__(256) void deltaWo_kernel(
    const float* __restrict__ dsel, const int* __restrict__ topb,
    const float* __restrict__ Wo, float* x1, int L, int u) {
  __shared__ float ds[64];
  int sel = blockIdx.x;  // (b*8+h)*u + r
  int bh = sel / u;
  int b = bh >> 3, h = bh & 7;
  int t = topb[sel];
  int tid = threadIdx.x;
  if (tid < 64) ds[tid] = dsel[sel * HD + tid];
  __syncthreads();
  float* row = x1 + ((size_t)(b * L + t)) * DMODEL;
  for (int nn = 0; nn < 2; nn++) {
    int n = tid + nn * 256;
    const float* wr = Wo + (size_t)n * 512 + h * HD;
    float a = 0.f;
#pragma unroll
    for (int k = 0; k < 64; k += 4) {
      float4 w4 = *(const float4*)(wr + k);
      a += ds[k] * w4.x + ds[k + 1] * w4.y + ds[k + 2] * w4.z + ds[k + 3] * w4.w;
    }
    atomicAdd(row + n, a);
  }
}

// ---------------------------------------------------------------- layernorm (512 cols)
__global__ __launch_bounds__(256) void ln_kernel(const float* __restrict__ X,
                                                 const float* __restrict__ g,
                                                 const float* __restrict__ bta,
                                                 float* __restrict__ Y) {
  __shared__ float red[256];
  int row = blockIdx.x, tid = threadIdx.x;
  size_t base = (size_t)row * DMODEL;
  float x0 = X[base + tid], x1 = X[base + tid + 256];
  red[tid] = x0 + x1;
  __syncthreads();
  for (int s = 128; s > 0; s >>= 1) {
    if (tid < s) red[tid] += red[tid + s];
    __syncthreads();
  }
  float mean = red[0] * (1.0f / 512.0f);
  __syncthreads();
  float d0 = x0 - mean, d1 = x1 - mean;
  red[tid] = d0 * d0 + d1 * d1;
  __syncthreads();
  for (int s = 128; s > 0; s >>= 1) {
    if (tid < s) red[tid] += red[tid + s];
    __syncthreads();
  }
  float inv = 1.0f / sqrtf(red[0] * (1.0f / 512.0f) + 1e-5f);
  Y[base + tid] = d0 * inv * g[tid] + bta[tid];
  Y[base + tid + 256] = d1 * inv * g[tid + 256] + bta[tid + 256];
}

// ---------------------------------------------------------------- BN stats + pool
__global__ __launch_bounds__(256) void bnpart_kernel(const float* __restrict__ z,
                                                     float* __restrict__ psum,
                                                     float* __restrict__ psq,
                                                     int rowsPer) {
  int blk = blockIdx.x, tid = threadIdx.x;
  size_t r0 = (size_t)blk * rowsPer;
  float s0 = 0, q0 = 0, s1 = 0, q1 = 0;
  for (int r = 0; r < rowsPer; r++) {
    const float* zp = z + (r0 + r) * DMODEL;
    float a = zp[tid];
    s0 += a; q0 += a * a;
    float c = zp[tid + 256];
    s1 += c; q1 += c * c;
  }
  psum[blk * DMODEL + tid] = s0;
  psum[blk * DMODEL + tid + 256] = s1;
  psq[blk * DMODEL + tid] = q0;
  psq[blk * DMODEL + tid + 256] = q1;
}

__global__ void bnfin_kernel(const float* __restrict__ psum,
                             const float* __restrict__ psq, float* __restrict__ mu,
                             float* __restrict__ var, int nb, int Rtot) {
  int c = blockIdx.x * 256 + threadIdx.x;
  float s = 0, q = 0;
  for (int b = 0; b < nb; b++) {
    s += psum[b * DMODEL + c];
    q += psq[b * DMODEL + c];
  }
  float m = s / (float)Rtot;
  mu[c] = m;
  var[c] = fmaxf(q / (float)Rtot - m * m, 0.f);
}

__global__ void bnpool_kernel(const float* __restrict__ z,
                              const float* __restrict__ mu,
                              const float* __restrict__ var,
                              const float* __restrict__ g,
                              const float* __restrict__ bta,
                              float* __restrict__ out, int L) {
  int gid = blockIdx.x * 256 + threadIdx.x;  // B*(L/2)*512
  int c = gid & 511;
  int bt = gid >> 9;
  int L2 = L >> 1;
  int t2 = bt % L2, b = bt / L2;
  float m = mu[c];
  float inv = 1.0f / sqrtf(var[c] + 1e-5f);
  float gg = g[c], bb = bta[c];
  float best = -3.4e38f;
#pragma unroll
  for (int ww = 0; ww < 3; ww++) {
    int t = 2 * t2 - 1 + ww;
    if (t < 0 || t >= L) continue;
    float yv = (z[((size_t)(b * L + t)) * DMODEL + c] - m) * inv * gg + bb;
    yv = (yv > 0.f) ? yv : expm1f(yv);
    best = fmaxf(best, yv);
  }
  out[gid] = best;
}

// ---------------------------------------------------------------- final projection (512 -> 7)
__global__ __launch_bounds__(64) void end_kernel(const float* __restrict__ xn,
                                                 const float* __restrict__ ew,
                                                 const float* __restrict__ eb,
                                                 float* __restrict__ out) {
  __shared__ float xs[512];
  __shared__ float red[64];
  int row = blockIdx.x, tid = threadIdx.x;
#pragma unroll
  for (int i = 0; i < 8; i++) xs[tid + 64 * i] = xn[(size_t)row * DMODEL + tid + 64 * i];
  __syncthreads();
  for (int c = 0; c < 7; c++) {
    float p = 0.f;
    for (int d = tid; d < 512; d += 64) p += xs[d] * ew[c * DMODEL + d];
    red[tid] = p;
    __syncthreads();
    for (int s = 32; s > 0; s >>= 1) {
      if (tid < s) red[tid] += red[tid + s];
      __syncthreads();
    }
    if (tid == 0) out[row * 7 + c] = red[0] + eb[c];
    __syncthreads();
  }
}

// ---------------------------------------------------------------- host
extern "C" void kernel_launch(void* const* d_in, const int* in_sizes, int n_in,
                              void* d_out, int out_size, void* d_ws,
                              size_t ws_size, hipStream_t stream) {
  (void)in_sizes; (void)n_in; (void)out_size; (void)ws_size;
  const float* x_enc = (const float*)d_in[0];
  const float* tok_w = (const float*)d_in[1];
  const float* Wq = (const float*)d_in[2];
  const float* bq = (const float*)d_in[3];
  const float* Wk = (const float*)d_in[4];
  const float* bk = (const float*)d_in[5];
  const float* Wv = (const float*)d_in[6];
  const float* bv = (const float*)d_in[7];
  const float* Wo = (const float*)d_in[8];
  const float* bo = (const float*)d_in[9];
  const float* w1 = (const float*)d_in[10];
  const float* b1 = (const float*)d_in[11];
  const float* w2 = (const float*)d_in[12];
  const float* b2 = (const float*)d_in[13];
  const float* g1 = (const float*)d_in[14];
  const float* be1 = (const float*)d_in[15];
  const float* g2 = (const float*)d_in[16];
  const float* be2 = (const float*)d_in[17];
  const float* dw = (const float*)d_in[18];
  const float* db = (const float*)d_in[19];
  const float* bng = (const float*)d_in[20];
  const float* bnb = (const float*)d_in[21];
  const float* lnfg = (const float*)d_in[22];
  const float* lnfb = (const float*)d_in[23];
  const float* endw = (const float*)d_in[24];
  const float* endb = (const float*)d_in[25];
  float* out = (float*)d_out;
  char* ws = (char*)d_ws;

  const int NCH = 8;  // attention key chunks

  // ---- arena (~108 MB) ----
  size_t o = 0;
  float* buf0 = (float*)(ws + o); o += (size_t)16384 * 512 * 4;  // x / CH(4096x2048)
  float* qbuf = (float*)(ws + o); o += (size_t)16384 * 512 * 4;  // Q / V / xa
  float* kbuf = (float*)(ws + o); o += (size_t)16384 * 512 * 4;  // K / x1=z
  float* wpack = (float*)(ws + o); o += (size_t)512 * 1536 * 4;
  float* Mb    = (float*)(ws + o); o += (size_t)64 * 2048 * 4;
  int*   idxb  = (int*)(ws + o);   o += (size_t)2048 * 24 * 4;
  int*   topb  = (int*)(ws + o);   o += 8192;
  float* qsel  = (float*)(ws + o); o += (size_t)64 * 24 * 64 * 4;
  float* dsel  = (float*)(ws + o); o += (size_t)64 * 24 * 64 * 4;
  float* mvg   = (float*)(ws + o); o += (size_t)8 * 512 * 4;
  float* mvWog = (float*)(ws + o); o += (size_t)8 * 512 * 4;
  float* psumx = (float*)(ws + o); o += (size_t)64 * 512 * 4;
  float* psum  = (float*)(ws + o); o += (size_t)128 * 512 * 4;
  float* psq   = (float*)(ws + o); o += (size_t)128 * 512 * 4;
  float* muv   = (float*)(ws + o); o += 2048;
  float* varv  = (float*)(ws + o); o += 2048;
  float* pmb   = (float*)(ws + o); o += (size_t)64 * NCH * 24 * 4;
  float* plb   = (float*)(ws + o); o += (size_t)64 * NCH * 24 * 4;
  float* pOb   = (float*)(ws + o); o += (size_t)64 * NCH * 24 * 64 * 4;  // 3.1 MB

  const int B = 8;
  const int S = 2048;
  tokpe_kernel<<<B * S * DMODEL / 256, 256, 0, stream>>>(x_enc, tok_w, buf0, S);

  int L = S;
  const int Uarr[3] = {24, 21, 21};  // 3*ceil(ln(L)) for 2048,1024,512
  for (int l = 0; l < 3; l++) {
    int U = Uarr[l];
    int u = Uarr[l];
    int BL = B * L;
    int nty = BL / 128;  // 128 / 64 / 32
    idx_kernel<<<(L * U + 255) / 256, 256, 0, stream>>>(idxb, L * U, l, L - 1);

    // Q, K (full batch)
    gemm128<0, 0, 0><<<4 * nty, 256, 0, stream>>>(
        buf0, Wq + (size_t)l * 262144, bq + l * 512, nullptr, qbuf, 512, 512, 0,
        4, nty);
    gemm128<0, 0, 0><<<4 * nty, 256, 0, stream>>>(
        buf0, Wk + (size_t)l * 262144, bk + l * 512, nullptr, kbuf, 512, 512, 0,
        4, nty);
    mscore_kernel<<<8 * 8 * L / 256, 256, 0, stream>>>(qbuf, kbuf, idxb, Mb, L, U);
    topk_kernel<<<64, 256, 0, stream>>>(Mb, topb, L, u);
    gatherq_kernel<<<64 * u, 64, 0, stream>>>(qbuf, topb, qsel, L, u);
    xmean_kernel<<<64, 256, 0, stream>>>(buf0, psumx, L);
    mvmake_kernel<<<8, 256, 0, stream>>>(psumx, Wv + (size_t)l * 262144,
                                         bv + l * 512, Wo + (size_t)l * 262144,
                                         bo + l * 512, mvg, mvWog, L);
    // V (overwrites Q buffer; qsel already gathered)
    gemm128<0, 0, 0><<<4 * nty, 256, 0, stream>>>(
        buf0, Wv + (size_t)l * 262144, bv + l * 512, nullptr, qbuf, 512, 512, 0,
        4, nty);
    attnflash_kernel<<<64 * NCH, 256, 0, stream>>>(qsel, kbuf, qbuf, pmb, plb,
                                                   pOb, L, u, NCH);
    attncomb_kernel<<<64 * u, 64, 0, stream>>>(pmb, plb, pOb, mvg, dsel, u, NCH);
    // x1 = x + mvWo (into kbuf, K no longer needed) ; += sparse delta@Wo
    x1bcast_kernel<<<BL * 512 / 256, 256, 0, stream>>>(buf0, mvWog, kbuf, L);
    deltaWo_kernel<<<64 * u, 256, 0, stream>>>(dsel, topb,
                                               Wo + (size_t)l * 262144, kbuf, L, u);
    // xa = LN1(x1) -> qbuf
    ln_kernel<<<BL, 256, 0, stream>>>(kbuf, g1 + l * 512, be1 + l * 512, qbuf);
    // FFN, 4096-row chunks; CH = buf0 (x dead). Residual is xa (qbuf)!
    for (int r0 = 0; r0 < BL; r0 += 4096) {
      gemm128<1, 0, 0><<<16 * 32, 256, 0, stream>>>(
          qbuf + (size_t)r0 * 512, w1 + (size_t)l * 2048 * 512, b1 + l * 2048,
          nullptr, buf0, 2048, 512, 0, 16, 32);
      gemm128<0, 1, 0><<<4 * 32, 256, 0, stream>>>(
          buf0, w2 + (size_t)l * 512 * 2048, b2 + l * 512,
          qbuf + (size_t)r0 * 512, kbuf + (size_t)r0 * 512, 512, 2048, 0, 4, 32);
    }
    // x = LN2(z) -> buf0
    ln_kernel<<<BL, 256, 0, stream>>>(kbuf, g2 + l * 512, be2 + l * 512, buf0);

    if (l < 2) {
      packw_kernel<<<512 * 1536 / 256, 256, 0, stream>>>(
          dw + (size_t)l * 512 * 512 * 3, wpack);
      gemm128<0, 0, 1><<<4 * nty, 256, 0, stream>>>(
          buf0, wpack, db + l * 512, nullptr, kbuf, 512, 1536, L - 1, 4, nty);
      int nb = BL / 128;
      bnpart_kernel<<<nb, 256, 0, stream>>>(kbuf, psum, psq, 128);
      bnfin_kernel<<<2, 256, 0, stream>>>(psum, psq, muv, varv, nb, BL);
      bnpool_kernel<<<(BL / 2) * 512 / 256, 256, 0, stream>>>(
          kbuf, muv, varv, bng + l * 512, bnb + l * 512, buf0, L);
      L >>= 1;
    }
  }
  int BL = B * L;  // 4096
  ln_kernel<<<BL, 256, 0, stream>>>(buf0, lnfg, lnfb, qbuf);
  end_kernel<<<BL, 64, 0, stream>>>(qbuf, endw, endb, out);
}

// Round 12
// 4094.012 us; speedup vs baseline: 1.3375x; 1.1706x over previous
//
#include <hip/hip_runtime.h>
#include <cstdint>
#include <cstddef>

#define DMODEL 512
#define NHEAD 8
#define HD 64

// ---------------------------------------------------------------- threefry
__device__ __forceinline__ uint32_t rotl32(uint32_t x, int r) {
  return (x << r) | (x >> (32 - r));
}

__device__ __forceinline__ void tf_block(uint32_t k0, uint32_t k1,
                                         uint32_t& x0, uint32_t& x1) {
  uint32_t ks0 = k0, ks1 = k1, ks2 = k0 ^ k1 ^ 0x1BD11BDAu;
  x0 += ks0; x1 += ks1;
  x0 += x1; x1 = rotl32(x1, 13); x1 ^= x0;
  x0 += x1; x1 = rotl32(x1, 15); x1 ^= x0;
  x0 += x1; x1 = rotl32(x1, 26); x1 ^= x0;
  x0 += x1; x1 = rotl32(x1, 6);  x1 ^= x0;
  x0 += ks1; x1 += ks2 + 1u;
  x0 += x1; x1 = rotl32(x1, 17); x1 ^= x0;
  x0 += x1; x1 = rotl32(x1, 29); x1 ^= x0;
  x0 += x1; x1 = rotl32(x1, 16); x1 ^= x0;
  x0 += x1; x1 = rotl32(x1, 24); x1 ^= x0;
  x0 += ks2; x1 += ks0 + 2u;
  x0 += x1; x1 = rotl32(x1, 13); x1 ^= x0;
  x0 += x1; x1 = rotl32(x1, 15); x1 ^= x0;
  x0 += x1; x1 = rotl32(x1, 26); x1 ^= x0;
  x0 += x1; x1 = rotl32(x1, 6);  x1 ^= x0;
  x0 += ks0; x1 += ks1 + 3u;
  x0 += x1; x1 = rotl32(x1, 17); x1 ^= x0;
  x0 += x1; x1 = rotl32(x1, 29); x1 ^= x0;
  x0 += x1; x1 = rotl32(x1, 16); x1 ^= x0;
  x0 += x1; x1 = rotl32(x1, 24); x1 ^= x0;
  x0 += ks1; x1 += ks2 + 4u;
  x0 += x1; x1 = rotl32(x1, 13); x1 ^= x0;
  x0 += x1; x1 = rotl32(x1, 15); x1 ^= x0;
  x0 += x1; x1 = rotl32(x1, 26); x1 ^= x0;
  x0 += x1; x1 = rotl32(x1, 6);  x1 ^= x0;
  x0 += ks2; x1 += ks0 + 5u;
}

__global__ void idx_kernel(int* __restrict__ idxb, int n, int layer, int mask) {
  int e = blockIdx.x * 256 + threadIdx.x;
  if (e >= n) return;
  uint32_t f0 = 0u, f1 = (uint32_t)layer;
  tf_block(0u, 42u, f0, f1);
  uint32_t s0 = 0u, s1 = 1u;
  tf_block(f0, f1, s0, s1);
  uint32_t x0 = 0u, x1 = (uint32_t)e;
  tf_block(s0, s1, x0, x1);
  uint32_t bits = x0 ^ x1;
  idxb[e] = (int)(bits & (uint32_t)mask);
}

// ---------------------------------------------------------------- GEMM 128x128 (XCD-swizzled, optional K-split)
// Non-PART: C[m,n] = act( sum_k A[m,k]*W[n,k] + bias[n] + (HASR ? R[m,n] : 0) )
// PART: block kb computes raw partial over K-slice [kb*kloop, (kb+1)*kloop) into
//       Cpart + kb*rows*N (no bias/act/res); combine_kernel sums deterministically.
// CONV: logical A[r][k] = x[bbase + ((t-1+w)&Lmask)][k&511], w=k>>9 (K=1536).
__device__ __forceinline__ float gelu_f(float v) {
  return 0.5f * v * (1.0f + erff(v * 0.7071067811865476f));
}

template <int ACT, int HASR, int CONV, int PART>
__global__ __launch_bounds__(256, 2) void gemm128(
    const float* __restrict__ A, const float* __restrict__ W,
    const float* __restrict__ bias, const float* Rres, float* C,
    int N, int K, int Lmask, int ntx, int nty, int kloop, int ks) {
  __shared__ float As[16][140];
  __shared__ float Ws[16][140];
  const int tid = threadIdx.x;
  int blk = blockIdx.x;
  const int tiles = ntx * nty;
  int kb = 0;
  if (PART) { kb = blk / tiles; blk -= kb * tiles; }
  const int koff = kb * kloop;
  const int xcd = blk & 7;
  const int j = blk >> 3;
  const int jr = j / ntx;
  const int row_t = xcd * (nty >> 3) + jr;
  const int col_t = j - jr * ntx;
  const int row0 = row_t * 128, col0 = col_t * 128;

  const int ar = tid >> 1;        // 0..127
  const int ac = (tid & 1) << 3;  // 0 / 8
  const int arp = ar + ((ar >> 5) << 2);        // skewed store col
  const int tx = tid & 15, ty = tid >> 4;
  const int wcol = tx * 8 + ((tx >> 2) << 2);   // skewed read col (W frag)
  const int acol = ty * 8 + ((ty >> 2) << 2);   // skewed read col (A frag)
  const int arow = row0 + ar;
  const float* Wp = W + (size_t)(col0 + ar) * K + koff + ac;
  const float* Ap = A + (size_t)arow * K + koff + ac;
  int tcv = 0, bbase = 0;
  if (CONV) { tcv = arow & Lmask; bbase = arow & ~Lmask; }
  float4 ra0, ra1, rw0, rw1;
  float acc[8][8] = {};
  const int T = kloop >> 4;

  {
    const float* ap;
    if (CONV) {
      int kabs = koff;
      int w = kabs >> 9;
      int src = bbase | ((tcv - 1 + w) & Lmask);
      ap = A + (size_t)src * 512 + (kabs & 511) + ac;
    } else {
      ap = Ap;
    }
    ra0 = *(const float4*)(ap);
    ra1 = *(const float4*)(ap + 4);
    rw0 = *(const float4*)(Wp);
    rw1 = *(const float4*)(Wp + 4);
  }

  for (int it = 0; it < T; ++it) {
#pragma unroll
    for (int q = 0; q < 4; q++) {
      As[ac + q][arp] = ((float*)&ra0)[q];
      As[ac + 4 + q][arp] = ((float*)&ra1)[q];
      Ws[ac + q][arp] = ((float*)&rw0)[q];
      Ws[ac + 4 + q][arp] = ((float*)&rw1)[q];
    }
    __syncthreads();
    if (it + 1 < T) {
      const int k0 = (it + 1) << 4;
      const float* ap;
      if (CONV) {
        int kabs = koff + k0;
        int w = kabs >> 9;
        int src = bbase | ((tcv - 1 + w) & Lmask);
        ap = A + (size_t)src * 512 + (kabs & 511) + ac;
      } else {
        ap = Ap + k0;
      }
      ra0 = *(const float4*)(ap);
      ra1 = *(const float4*)(ap + 4);
      rw0 = *(const float4*)(Wp + k0);
      rw1 = *(const float4*)(Wp + k0 + 4);
    }
#pragma unroll
    for (int k = 0; k < 16; k++) {
      float av[8], wv[8];
      *(float4*)(av) = *(const float4*)&As[k][acol];
      *(float4*)(av + 4) = *(const float4*)&As[k][acol + 4];
      *(float4*)(wv) = *(const float4*)&Ws[k][wcol];
      *(float4*)(wv + 4) = *(const float4*)&Ws[k][wcol + 4];
#pragma unroll
      for (int i = 0; i < 8; i++)
#pragma unroll
        for (int q = 0; q < 8; q++) acc[i][q] += av[i] * wv[q];
    }
    __syncthreads();
  }

  if (PART) {
    float* Cp = C + (size_t)kb * (nty << 7) * N;
#pragma unroll
    for (int i = 0; i < 8; i++) {
      const int m = row0 + ty * 8 + i;
      const int c0 = col0 + tx * 8;
      *(float4*)(Cp + (size_t)m * N + c0) = *(float4*)(&acc[i][0]);
      *(float4*)(Cp + (size_t)m * N + c0 + 4) = *(float4*)(&acc[i][4]);
    }
  } else {
#pragma unroll
    for (int i = 0; i < 8; i++) {
      const int m = row0 + ty * 8 + i;
      const int c0 = col0 + tx * 8;
      float vout[8];
#pragma unroll
      for (int q = 0; q < 8; q++) {
        float v = acc[i][q] + bias[c0 + q];
        if (HASR) v += Rres[(size_t)m * N + c0 + q];
        if (ACT == 1) v = gelu_f(v);
        vout[q] = v;
      }
      *(float4*)(C + (size_t)m * N + c0) = *(float4*)(vout);
      *(float4*)(C + (size_t)m * N + c0 + 4) = *(float4*)(vout + 4);
    }
  }
}

// combine K-split partials: out = sum_kb part[kb] + bias (+ residual). N=512.
template <int HASR>
__global__ __launch_bounds__(256) void combine_kernel(
    const float* __restrict__ part, const float* __restrict__ bias,
    const float* Rres, float* __restrict__ Cout, size_t MN, int ks) {
  size_t gid = (size_t)blockIdx.x * 256 + threadIdx.x;
  int c = (int)(gid & 511);
  float v = 0.f;
  for (int kb = 0; kb < ks; kb++) v += part[kb * MN + gid];
  v += bias[c];
  if (HASR) v += Rres[gid];
  Cout[gid] = v;
}

// ---------------------------------------------------------------- token conv + pos embed
__global__ void tokpe_kernel(const float* __restrict__ xe,
                             const float* __restrict__ w,
                             float* __restrict__ out, int S) {
  int gid = blockIdx.x * 256 + threadIdx.x;  // B*S*512
  int o = gid & 511;
  int bt = gid >> 9;
  int t = bt % S, b = bt / S;
  float acc = 0.f;
#pragma unroll
  for (int ww = 0; ww < 3; ww++) {
    int tt = t - 1 + ww;
    tt = (tt < 0) ? tt + S : (tt >= S ? tt - S : tt);
    const float* xr = xe + ((size_t)(b * S + tt)) * 7;
#pragma unroll
    for (int i = 0; i < 7; i++) acc += xr[i] * w[o * 21 + i * 3 + ww];
  }
  int i2 = o >> 1;
  float dv = expf((float)(2 * i2) * (-9.210340371976184f / 512.0f));
  float ang = (float)t * dv;
  acc += (o & 1) ? cosf(ang) : sinf(ang);
  out[gid] = acc;
}

// ---------------------------------------------------------------- conv weight pack
__global__ void packw_kernel(const float* __restrict__ dw, float* __restrict__ wp) {
  int gid = blockIdx.x * 256 + threadIdx.x;  // 512*1536
  int o = gid / 1536;
  int kk = gid - o * 1536;
  int ww = kk / 512;
  int c = kk - ww * 512;
  wp[gid] = dw[((size_t)o * 512 + c) * 3 + ww];
}

// ---------------------------------------------------------------- M score, all batches (b = blk&7 for XCD locality)
__global__ __launch_bounds__(256) void mscore_kernel(
    const float* __restrict__ Q, const float* __restrict__ Kb,
    const int* __restrict__ idxb, float* __restrict__ Mout, int L, int U) {
  int i = blockIdx.x;
  int b = i & 7;
  int j = i >> 3;
  int chunks = L >> 8;
  int h = j / chunks;
  int c = j - h * chunks;
  int t = c * 256 + threadIdx.x;
  const float4* qr = (const float4*)(Q + ((size_t)(b * L + t)) * DMODEL + h * HD);
  float4 qv[16];
#pragma unroll
  for (int ii = 0; ii < 16; ii++) qv[ii] = qr[ii];
  float mx = -3.4e38f, sm = 0.f;
  for (int jj = 0; jj < U; jj++) {
    int kr = idxb[t * U + jj];
    const float4* kp =
        (const float4*)(Kb + ((size_t)(b * L + kr)) * DMODEL + h * HD);
    float dot = 0.f;
#pragma unroll
    for (int ii = 0; ii < 16; ii++) {
      float4 kv = kp[ii];
      dot += qv[ii].x * kv.x + qv[ii].y * kv.y + qv[ii].z * kv.z + qv[ii].w * kv.w;
    }
    mx = fmaxf(mx, dot);
    sm += dot;
  }
  Mout[(size_t)(b * 8 + h) * L + t] = mx - sm / (float)L;
}

// ---------------------------------------------------------------- top-k (per b,h), register-resident
__global__ __launch_bounds__(256) void topk_kernel(const float* __restrict__ Mv,
                                                   int* __restrict__ topb, int L,
                                                   int u) {
  __shared__ float wv_s[4];
  __shared__ int wi_s[4];
  __shared__ int best_s;
  int bh = blockIdx.x, tid = threadIdx.x;
  int lane = tid & 63, w = tid >> 6;
  int cnt = L >> 8;  // 8 / 4 / 2
  float lv[8];
  for (int i = 0; i < cnt; i++) lv[i] = Mv[(size_t)bh * L + i * 256 + tid];
  for (int r = 0; r < u; r++) {
    float bv = -3.4e38f;
    int bi = 0x7fffffff;
    for (int i = 0; i < cnt; i++) {
      if (lv[i] > bv) { bv = lv[i]; bi = i * 256 + tid; }
    }
    for (int s = 32; s > 0; s >>= 1) {
      float ov = __shfl_down(bv, s);
      int oi = __shfl_down(bi, s);
      if (ov > bv || (ov == bv && oi < bi)) { bv = ov; bi = oi; }
    }
    if (lane == 0) { wv_s[w] = bv; wi_s[w] = bi; }
    __syncthreads();
    if (tid == 0) {
      float fv = wv_s[0];
      int fi = wi_s[0];
      for (int q = 1; q < 4; q++) {
        if (wv_s[q] > fv || (wv_s[q] == fv && wi_s[q] < fi)) {
          fv = wv_s[q];
          fi = wi_s[q];
        }
      }
      best_s = fi;
      topb[bh * u + r] = fi;
    }
    __syncthreads();
    int win = best_s;
    if ((win & 255) == tid) lv[win >> 8] = -3.4e38f;
  }
}

// ---------------------------------------------------------------- gather selected q rows
__global__ void gatherq_kernel(const float* __restrict__ Q,
                               const int* __restrict__ topb,
                               float* __restrict__ qsel, int L, int u) {
  int i = blockIdx.x;  // (b*8+h)*u + r
  int bh = i / u;
  int b = bh >> 3, h = bh & 7;
  int t = topb[i];
  qsel[i * HD + threadIdx.x] =
      Q[((size_t)(b * L + t)) * DMODEL + h * HD + threadIdx.x];
}

// ---------------------------------------------------------------- mean of x rows per batch (partial)
__global__ __launch_bounds__(256) void xmean_kernel(const float* __restrict__ x,
                                                    float* __restrict__ psumx,
                                                    int L) {
  int i = blockIdx.x;  // 64: b*8+g
  int b = i >> 3, g = i & 7;
  int rows = L >> 3;
  int tid = threadIdx.x;
  const float* base = x + ((size_t)b * L + (size_t)g * rows) * DMODEL;
  float s0 = 0.f, s1 = 0.f;
  for (int t = 0; t < rows; t++) {
    s0 += base[(size_t)t * DMODEL + tid];
    s1 += base[(size_t)t * DMODEL + tid + 256];
  }
  psumx[i * DMODEL + tid] = s0;
  psumx[i * DMODEL + tid + 256] = s1;
}

// mv = xmean@Wv^T + bv ; mvWo = mv@Wo^T + bo
__global__ __launch_bounds__(256) void mvmake_kernel(
    const float* __restrict__ psumx, const float* __restrict__ Wv,
    const float* __restrict__ bv, const float* __restrict__ Wo,
    const float* __restrict__ bo, float* __restrict__ mvg,
    float* __restrict__ mvWog, int L) {
  __shared__ float xm[512];
  __shared__ float mvs[512];
  int b = blockIdx.x, tid = threadIdx.x;
  float inv = 1.0f / (float)L;
  for (int nn = 0; nn < 2; nn++) {
    int c = tid + nn * 256;
    float s = 0.f;
    for (int g = 0; g < 8; g++) s += psumx[(b * 8 + g) * DMODEL + c];
    xm[c] = s * inv;
  }
  __syncthreads();
  for (int nn = 0; nn < 2; nn++) {
    int n = tid + nn * 256;
    const float* wr = Wv + (size_t)n * 512;
    float s = bv[n];
    for (int k = 0; k < 512; k += 4) {
      float4 w4 = *(const float4*)(wr + k);
      s += xm[k] * w4.x + xm[k + 1] * w4.y + xm[k + 2] * w4.z + xm[k + 3] * w4.w;
    }
    mvs[n] = s;
    mvg[b * DMODEL + n] = s;
  }
  __syncthreads();
  for (int nn = 0; nn < 2; nn++) {
    int n = tid + nn * 256;
    const float* wr = Wo + (size_t)n * 512;
    float s = bo[n];
    for (int k = 0; k < 512; k += 4) {
      float4 w4 = *(const float4*)(wr + k);
      s += mvs[k] * w4.x + mvs[k + 1] * w4.y + mvs[k + 2] * w4.z +
           mvs[k + 3] * w4.w;
    }
    mvWog[b * DMODEL + n] = s;
  }
}

// x1 = x + mvWo[b] (broadcast)
__global__ void x1bcast_kernel(const float* __restrict__ x,
                               const float* __restrict__ mvWog,
                               float* __restrict__ x1, int L) {
  int gid = blockIdx.x * 256 + threadIdx.x;  // BL*512
  int c = gid & 511;
  int r = gid >> 9;
  int b = r / L;
  x1[gid] = x[gid] + mvWog[b * DMODEL + c];
}

// ---------------------------------------------------------------- chunked flash attention for selected rows
__global__ __launch_bounds__(256) void attnflash_kernel(
    const float* __restrict__ qsel, const float* __restrict__ Kb,
    const float* __restrict__ Vb, float* __restrict__ pm,
    float* __restrict__ pl, float* __restrict__ pO, int L, int u, int nchunk) {
  __shared__ float qs[24][64];
  __shared__ float Kt[64][68];   // transposed K tile: Kt[d][j]
  __shared__ float Ps[24][68];   // P row per query (wave-local rows)
  int blk = blockIdx.x;          // bh*nchunk + c
  int bh = blk / nchunk;
  int c = blk - bh * nchunk;
  int b = bh >> 3, h = bh & 7;
  int cs = L / nchunk;
  int tid = threadIdx.x;
  int lane = tid & 63;
  int w = tid >> 6;
  for (int i = tid; i < u * 64; i += 256)
    qs[i >> 6][i & 63] = qsel[(size_t)bh * u * 64 + i];
  float m[6], l[6], O[6];
#pragma unroll
  for (int k = 0; k < 6; k++) { m[k] = -3.4e38f; l[k] = 0.f; O[k] = 0.f; }
  const float* Kbase = Kb + (size_t)b * L * DMODEL + h * HD;
  const float* Vbase = Vb + (size_t)b * L * DMODEL + h * HD;
  const int jrow = tid & 63;        // staging row
  const int dch = (tid >> 6) << 4;  // staging d-chunk base (0,16,32,48)
  for (int j0 = c * cs; j0 < (c + 1) * cs; j0 += 64) {
    __syncthreads();  // protect Kt (and qs on first iter)
    const float* kr = Kbase + (size_t)(j0 + jrow) * DMODEL + dch;
    float4 k0 = *(const float4*)(kr);
    float4 k1 = *(const float4*)(kr + 4);
    float4 k2 = *(const float4*)(kr + 8);
    float4 k3 = *(const float4*)(kr + 12);
#pragma unroll
    for (int q = 0; q < 4; q++) {
      Kt[dch + q][jrow] = ((float*)&k0)[q];
      Kt[dch + 4 + q][jrow] = ((float*)&k1)[q];
      Kt[dch + 8 + q][jrow] = ((float*)&k2)[q];
      Kt[dch + 12 + q][jrow] = ((float*)&k3)[q];
    }
    __syncthreads();
#pragma unroll
    for (int k = 0; k < 6; k++) {
      int qi = 4 * k + w;
      if (qi >= u) break;
      float s = 0.f;
#pragma unroll
      for (int d = 0; d < 64; d++) s += qs[qi][d] * Kt[d][lane];
      s *= 0.125f;
      float mx = s;
#pragma unroll
      for (int off = 32; off > 0; off >>= 1)
        mx = fmaxf(mx, __shfl_down(mx, off));
      mx = __shfl(mx, 0);
      float mnew = fmaxf(m[k], mx);
      float p = expf(s - mnew);
      float ps = p;
#pragma unroll
      for (int off = 32; off > 0; off >>= 1) ps += __shfl_down(ps, off);
      ps = __shfl(ps, 0);
      float alpha = expf(m[k] - mnew);
      l[k] = l[k] * alpha + ps;
      m[k] = mnew;
      O[k] *= alpha;
      Ps[qi][lane] = p;
    }
    for (int j = 0; j < 64; j += 4) {
      float v0 = Vbase[(size_t)(j0 + j) * DMODEL + lane];
      float v1 = Vbase[(size_t)(j0 + j + 1) * DMODEL + lane];
      float v2 = Vbase[(size_t)(j0 + j + 2) * DMODEL + lane];
      float v3 = Vbase[(size_t)(j0 + j + 3) * DMODEL + lane];
#pragma unroll
      for (int k = 0; k < 6; k++) {
        int qi = 4 * k + w;
        if (qi >= u) break;
        O[k] += Ps[qi][j] * v0 + Ps[qi][j + 1] * v1 + Ps[qi][j + 2] * v2 +
                Ps[qi][j + 3] * v3;
      }
    }
  }
#pragma unroll
  for (int k = 0; k < 6; k++) {
    int qi = 4 * k + w;
    if (qi < u) {
      int p = (bh * nchunk + c) * u + qi;
      if (lane == 0) { pm[p] = m[k]; pl[p] = l[k]; }
      pO[(size_t)p * 64 + lane] = O[k];
    }
  }
}

// combine chunk partials + scatter: x1[row] += (O/l - mv) @ Wo[:, h-block]^T
__global__ __launch_bounds__(256) void deltaWo_kernel(
    const float* __restrict__ pm, const float* __restrict__ pl,
    const float* __restrict__ pO, const float* __restrict__ mvg,
    const int* __restrict__ topb, const float* __restrict__ Wo, float* x1,
    int L, int u, int nchunk) {
  __shared__ float ds[64];
  int sel = blockIdx.x;  // (b*8+h)*u + qi
  int bh = sel / u;
  int qi = sel - bh * u;
  int b = bh >> 3, h = bh & 7;
  int t = topb[sel];
  int tid = threadIdx.x;
  if (tid < 64) {
    float mstar = -3.4e38f;
    for (int c = 0; c < nchunk; c++)
      mstar = fmaxf(mstar, pm[(bh * nchunk + c) * u + qi]);
    float lstar = 0.f, O = 0.f;
    for (int c = 0; c < nchunk; c++) {
      int p = (bh * nchunk + c) * u + qi;
      float wgt = expf(pm[p] - mstar);
      lstar += wgt * pl[p];
      O += wgt * pO[(size_t)p * 64 + tid];
    }
    ds[tid] = O / lstar - mvg[b * DMODEL + h * HD + tid];
  }
  __syncthreads();
  float* row = x1 + ((size_t)(b * L + t)) * DMODEL;
  for (int nn = 0; nn < 2; nn++) {
    int n = tid + nn * 256;
    const float* wr = Wo + (size_t)n * 512 + h * HD;
    float a = 0.f;
#pragma unroll
    for (int k = 0; k < 64; k += 4) {
      float4 w4 = *(const float4*)(wr + k);
      a += ds[k] * w4.x + ds[k + 1] * w4.y + ds[k + 2] * w4.z + ds[k + 3] * w4.w;
    }
    atomicAdd(row + n, a);
  }
}

// ---------------------------------------------------------------- layernorm (512 cols)
__global__ __launch_bounds__(256) void ln_kernel(const float* __restrict__ X,
                                                 const float* __restrict__ g,
                                                 const float* __restrict__ bta,
                                                 float* __restrict__ Y) {
  __shared__ float red[256];
  int row = blockIdx.x, tid = threadIdx.x;
  size_t base = (size_t)row * DMODEL;
  float x0 = X[base + tid], x1 = X[base + tid + 256];
  red[tid] = x0 + x1;
  __syncthreads();
  for (int s = 128; s > 0; s >>= 1) {
    if (tid < s) red[tid] += red[tid + s];
    __syncthreads();
  }
  float mean = red[0] * (1.0f / 512.0f);
  __syncthreads();
  float d0 = x0 - mean, d1 = x1 - mean;
  red[tid] = d0 * d0 + d1 * d1;
  __syncthreads();
  for (int s = 128; s > 0; s >>= 1) {
    if (tid < s) red[tid] += red[tid + s];
    __syncthreads();
  }
  float inv = 1.0f / sqrtf(red[0] * (1.0f / 512.0f) + 1e-5f);
  Y[base + tid] = d0 * inv * g[tid] + bta[tid];
  Y[base + tid + 256] = d1 * inv * g[tid + 256] + bta[tid + 256];
}

// ---------------------------------------------------------------- BN stats + pool
__global__ __launch_bounds__(256) void bnpart_kernel(const float* __restrict__ z,
                                                     float* __restrict__ psum,
                                                     float* __restrict__ psq,
                                                     int rowsPer) {
  int blk = blockIdx.x, tid = threadIdx.x;
  size_t r0 = (size_t)blk * rowsPer;
  float s0 = 0, q0 = 0, s1 = 0, q1 = 0;
  for (int r = 0; r < rowsPer; r++) {
    const float* zp = z + (r0 + r) * DMODEL;
    float a = zp[tid];
    s0 += a; q0 += a * a;
    float c = zp[tid + 256];
    s1 += c; q1 += c * c;
  }
  psum[blk * DMODEL + tid] = s0;
  psum[blk * DMODEL + tid + 256] = s1;
  psq[blk * DMODEL + tid] = q0;
  psq[blk * DMODEL + tid + 256] = q1;
}

__global__ void bnfin_kernel(const float* __restrict__ psum,
                             const float* __restrict__ psq, float* __restrict__ mu,
                             float* __restrict__ var, int nb, int Rtot) {
  int c = blockIdx.x * 256 + threadIdx.x;
  float s = 0, q = 0;
  for (int b = 0; b < nb; b++) {
    s += psum[b * DMODEL + c];
    q += psq[b * DMODEL + c];
  }
  float m = s / (float)Rtot;
  mu[c] = m;
  var[c] = fmaxf(q / (float)Rtot - m * m, 0.f);
}

__global__ void bnpool_kernel(const float* __restrict__ z,
                              const float* __restrict__ mu,
                              const float* __restrict__ var,
                              const float* __restrict__ g,
                              const float* __restrict__ bta,
                              float* __restrict__ out, int L) {
  int gid = blockIdx.x * 256 + threadIdx.x;  // B*(L/2)*512
  int c = gid & 511;
  int bt = gid >> 9;
  int L2 = L >> 1;
  int t2 = bt % L2, b = bt / L2;
  float m = mu[c];
  float inv = 1.0f / sqrtf(var[c] + 1e-5f);
  float gg = g[c], bb = bta[c];
  float best = -3.4e38f;
#pragma unroll
  for (int ww = 0; ww < 3; ww++) {
    int t = 2 * t2 - 1 + ww;
    if (t < 0 || t >= L) continue;
    float yv = (z[((size_t)(b * L + t)) * DMODEL + c] - m) * inv * gg + bb;
    yv = (yv > 0.f) ? yv : expm1f(yv);
    best = fmaxf(best, yv);
  }
  out[gid] = best;
}

// ---------------------------------------------------------------- final projection (512 -> 7)
__global__ __launch_bounds__(64) void end_kernel(const float* __restrict__ xn,
                                                 const float* __restrict__ ew,
                                                 const float* __restrict__ eb,
                                                 float* __restrict__ out) {
  __shared__ float xs[512];
  __shared__ float red[64];
  int row = blockIdx.x, tid = threadIdx.x;
#pragma unroll
  for (int i = 0; i < 8; i++) xs[tid + 64 * i] = xn[(size_t)row * DMODEL + tid + 64 * i];
  __syncthreads();
  for (int c = 0; c < 7; c++) {
    float p = 0.f;
    for (int d = tid; d < 512; d += 64) p += xs[d] * ew[c * DMODEL + d];
    red[tid] = p;
    __syncthreads();
    for (int s = 32; s > 0; s >>= 1) {
      if (tid < s) red[tid] += red[tid + s];
      __syncthreads();
    }
    if (tid == 0) out[row * 7 + c] = red[0] + eb[c];
    __syncthreads();
  }
}

// ---------------------------------------------------------------- host
extern "C" void kernel_launch(void* const* d_in, const int* in_sizes, int n_in,
                              void* d_out, int out_size, void* d_ws,
                              size_t ws_size, hipStream_t stream) {
  (void)in_sizes; (void)n_in; (void)out_size;
  const float* x_enc = (const float*)d_in[0];
  const float* tok_w = (const float*)d_in[1];
  const float* Wq = (const float*)d_in[2];
  const float* bq = (const float*)d_in[3];
  const float* Wk = (const float*)d_in[4];
  const float* bk = (const float*)d_in[5];
  const float* Wv = (const float*)d_in[6];
  const float* bv = (const float*)d_in[7];
  const float* Wo = (const float*)d_in[8];
  const float* bo = (const float*)d_in[9];
  const float* w1 = (const float*)d_in[10];
  const float* b1 = (const float*)d_in[11];
  const float* w2 = (const float*)d_in[12];
  const float* b2 = (const float*)d_in[13];
  const float* g1 = (const float*)d_in[14];
  const float* be1 = (const float*)d_in[15];
  const float* g2 = (const float*)d_in[16];
  const float* be2 = (const float*)d_in[17];
  const float* dw = (const float*)d_in[18];
  const float* db = (const float*)d_in[19];
  const float* bng = (const float*)d_in[20];
  const float* bnb = (const float*)d_in[21];
  const float* lnfg = (const float*)d_in[22];
  const float* lnfb = (const float*)d_in[23];
  const float* endw = (const float*)d_in[24];
  const float* endb = (const float*)d_in[25];
  float* out = (float*)d_out;
  char* ws = (char*)d_ws;

  const int NCH = 8;  // attention key chunks

  // ---- arena ----
  size_t o = 0;
  float* buf0 = (float*)(ws + o); o += (size_t)16384 * 512 * 4;  // x / CH(4096x2048)
  float* qbuf = (float*)(ws + o); o += (size_t)16384 * 512 * 4;  // Q / V / xa
  float* kbuf = (float*)(ws + o); o += (size_t)16384 * 512 * 4;  // K / x1=z
  float* wpack = (float*)(ws + o); o += (size_t)512 * 1536 * 4;
  float* Mb    = (float*)(ws + o); o += (size_t)64 * 2048 * 4;
  int*   idxb  = (int*)(ws + o);   o += (size_t)2048 * 24 * 4;
  int*   topb  = (int*)(ws + o);   o += 8192;
  float* qsel  = (float*)(ws + o); o += (size_t)64 * 24 * 64 * 4;
  float* mvg   = (float*)(ws + o); o += (size_t)8 * 512 * 4;
  float* mvWog = (float*)(ws + o); o += (size_t)8 * 512 * 4;
  float* psumx = (float*)(ws + o); o += (size_t)64 * 512 * 4;
  float* psum  = (float*)(ws + o); o += (size_t)128 * 512 * 4;
  float* psq   = (float*)(ws + o); o += (size_t)128 * 512 * 4;
  float* muv   = (float*)(ws + o); o += 2048;
  float* varv  = (float*)(ws + o); o += 2048;
  float* pmb   = (float*)(ws + o); o += (size_t)64 * NCH * 24 * 4;
  float* plb   = (float*)(ws + o); o += (size_t)64 * NCH * 24 * 4;
  float* pOb   = (float*)(ws + o); o += (size_t)64 * NCH * 24 * 64 * 4;
  float* partb = (float*)(ws + o); o += (size_t)4 * 4096 * 2048;  // 33.6 MB K-split partials
  const bool uks = (ws_size >= o);  // use K-split path only if workspace allows

  const int B = 8;
  const int S = 2048;
  tokpe_kernel<<<B * S * DMODEL / 256, 256, 0, stream>>>(x_enc, tok_w, buf0, S);

  int L = S;
  const int Uarr[3] = {24, 21, 21};  // 3*ceil(ln(L)) for 2048,1024,512
  for (int l = 0; l < 3; l++) {
    int U = Uarr[l];
    int u = Uarr[l];
    int BL = B * L;
    int nty = BL / 128;  // 128 / 64 / 32
    size_t MN = (size_t)BL * 512;
    int gq = 4 * nty;
    int ksq = (gq >= 512 || !uks) ? 1 : (512 / gq);  // 1 / 2 / 4
    idx_kernel<<<(L * U + 255) / 256, 256, 0, stream>>>(idxb, L * U, l, L - 1);

    // Q, K (full batch)
    if (ksq == 1) {
      gemm128<0, 0, 0, 0><<<gq, 256, 0, stream>>>(
          buf0, Wq + (size_t)l * 262144, bq + l * 512, nullptr, qbuf, 512, 512,
          0, 4, nty, 512, 1);
      gemm128<0, 0, 0, 0><<<gq, 256, 0, stream>>>(
          buf0, Wk + (size_t)l * 262144, bk + l * 512, nullptr, kbuf, 512, 512,
          0, 4, nty, 512, 1);
    } else {
      gemm128<0, 0, 0, 1><<<gq * ksq, 256, 0, stream>>>(
          buf0, Wq + (size_t)l * 262144, nullptr, nullptr, partb, 512, 512, 0,
          4, nty, 512 / ksq, ksq);
      combine_kernel<0><<<(unsigned)(MN / 256), 256, 0, stream>>>(
          partb, bq + l * 512, nullptr, qbuf, MN, ksq);
      gemm128<0, 0, 0, 1><<<gq * ksq, 256, 0, stream>>>(
          buf0, Wk + (size_t)l * 262144, nullptr, nullptr, partb, 512, 512, 0,
          4, nty, 512 / ksq, ksq);
      combine_kernel<0><<<(unsigned)(MN / 256), 256, 0, stream>>>(
          partb, bk + l * 512, nullptr, kbuf, MN, ksq);
    }
    mscore_kernel<<<8 * 8 * L / 256, 256, 0, stream>>>(qbuf, kbuf, idxb, Mb, L, U);
    topk_kernel<<<64, 256, 0, stream>>>(Mb, topb, L, u);
    gatherq_kernel<<<64 * u, 64, 0, stream>>>(qbuf, topb, qsel, L, u);
    xmean_kernel<<<64, 256, 0, stream>>>(buf0, psumx, L);
    mvmake_kernel<<<8, 256, 0, stream>>>(psumx, Wv + (size_t)l * 262144,
                                         bv + l * 512, Wo + (size_t)l * 262144,
                                         bo + l * 512, mvg, mvWog, L);
    // V (overwrites Q buffer; qsel already gathered)
    if (ksq == 1) {
      gemm128<0, 0, 0, 0><<<gq, 256, 0, stream>>>(
          buf0, Wv + (size_t)l * 262144, bv + l * 512, nullptr, qbuf, 512, 512,
          0, 4, nty, 512, 1);
    } else {
      gemm128<0, 0, 0, 1><<<gq * ksq, 256, 0, stream>>>(
          buf0, Wv + (size_t)l * 262144, nullptr, nullptr, partb, 512, 512, 0,
          4, nty, 512 / ksq, ksq);
      combine_kernel<0><<<(unsigned)(MN / 256), 256, 0, stream>>>(
          partb, bv + l * 512, nullptr, qbuf, MN, ksq);
    }
    attnflash_kernel<<<64 * NCH, 256, 0, stream>>>(qsel, kbuf, qbuf, pmb, plb,
                                                   pOb, L, u, NCH);
    // x1 = x + mvWo (into kbuf) ; += sparse delta@Wo (combine fused in)
    x1bcast_kernel<<<(unsigned)(MN / 256), 256, 0, stream>>>(buf0, mvWog, kbuf, L);
    deltaWo_kernel<<<64 * u, 256, 0, stream>>>(pmb, plb, pOb, mvg, topb,
                                               Wo + (size_t)l * 262144, kbuf, L,
                                               u, NCH);
    // xa = LN1(x1) -> qbuf
    ln_kernel<<<BL, 256, 0, stream>>>(kbuf, g1 + l * 512, be1 + l * 512, qbuf);
    // FFN, 4096-row chunks; CH = buf0 (x dead). Residual is xa (qbuf)!
    for (int r0 = 0; r0 < BL; r0 += 4096) {
      gemm128<1, 0, 0, 0><<<16 * 32, 256, 0, stream>>>(
          qbuf + (size_t)r0 * 512, w1 + (size_t)l * 2048 * 512, b1 + l * 2048,
          nullptr, buf0, 2048, 512, 0, 16, 32, 512, 1);
      if (uks) {
        // FFN2 K-split 4: 128 -> 512 blocks
        gemm128<0, 0, 0, 1><<<4 * 32 * 4, 256, 0, stream>>>(
            buf0, w2 + (size_t)l * 512 * 2048, nullptr, nullptr, partb, 512,
            2048, 0, 4, 32, 512, 4);
        combine_kernel<1><<<4096 * 512 / 256, 256, 0, stream>>>(
            partb, b2 + l * 512, qbuf + (size_t)r0 * 512,
            kbuf + (size_t)r0 * 512, (size_t)4096 * 512, 4);
      } else {
        gemm128<0, 1, 0, 0><<<4 * 32, 256, 0, stream>>>(
            buf0, w2 + (size_t)l * 512 * 2048, b2 + l * 512,
            qbuf + (size_t)r0 * 512, kbuf + (size_t)r0 * 512, 512, 2048, 0, 4,
            32, 2048, 1);
      }
    }
    // x = LN2(z) -> buf0
    ln_kernel<<<BL, 256, 0, stream>>>(kbuf, g2 + l * 512, be2 + l * 512, buf0);

    if (l < 2) {
      packw_kernel<<<512 * 1536 / 256, 256, 0, stream>>>(
          dw + (size_t)l * 512 * 512 * 3, wpack);
      int ksc = (gq >= 512 || !uks) ? 1 : 2;  // conv K=1536: split 2 when grid small
      if (ksc == 1) {
        gemm128<0, 0, 1, 0><<<gq, 256, 0, stream>>>(
            buf0, wpack, db + l * 512, nullptr, kbuf, 512, 1536, L - 1, 4, nty,
            1536, 1);
      } else {
        gemm128<0, 0, 1, 1><<<gq * 2, 256, 0, stream>>>(
            buf0, wpack, nullptr, nullptr, partb, 512, 1536, L - 1, 4, nty, 768,
            2);
        combine_kernel<0><<<(unsigned)(MN / 256), 256, 0, stream>>>(
            partb, db + l * 512, nullptr, kbuf, MN, 2);
      }
      int nb = BL / 128;
      bnpart_kernel<<<nb, 256, 0, stream>>>(kbuf, psum, psq, 128);
      bnfin_kernel<<<2, 256, 0, stream>>>(psum, psq, muv, varv, nb, BL);
      bnpool_kernel<<<(BL / 2) * 512 / 256, 256, 0, stream>>>(
          kbuf, muv, varv, bng + l * 512, bnb + l * 512, buf0, L);
      L >>= 1;
    }
  }
  int BL = B * L;  // 4096
  ln_kernel<<<BL, 256, 0, stream>>>(buf0, lnfg, lnfb, qbuf);
  end_kernel<<<BL, 64, 0, stream>>>(qbuf, endw, endb, out);
}